// Round 5
// baseline (1489.050 us; speedup 1.0000x reference)
//
#include <hip/hip_runtime.h>
#include <hip/hip_bf16.h>

#define FEAT 64
#define BK   128   // nodes per bucket (R5 edge-centric path)

typedef __bf16 bf16x8 __attribute__((ext_vector_type(8)));
typedef __bf16 bf16x4 __attribute__((ext_vector_type(4)));
typedef float  f32x4  __attribute__((ext_vector_type(4)));

// ---------------------------------------------------------------------------
// Zero kernel (hipMemsetAsync may execute at capture time -> poisoned replay).
// ---------------------------------------------------------------------------
__global__ __launch_bounds__(256)
void zero2_kernel(int* __restrict__ a, int* __restrict__ b, int n) {
    int i = blockIdx.x * 256 + threadIdx.x;
    if (i < n) { a[i] = 0; b[i] = 0; }
}

// ---------------------------------------------------------------------------
// detect + cast_w fused (block 0 sniffs int64-ness & zeroes the 1024-entry
// bucket counter array; blocks 1..16 cast the 4 weight matrices).
// ---------------------------------------------------------------------------
__global__ void detect_castw_kernel(const unsigned* __restrict__ w, int* __restrict__ flag,
                                    int* __restrict__ zcnt,
                                    const float* __restrict__ a, const float* __restrict__ b,
                                    const float* __restrict__ c, const float* __restrict__ d,
                                    __bf16* __restrict__ o) {
    if (blockIdx.x == 0) {
        __shared__ int any_nz;
        if (threadIdx.x == 0) any_nz = 0;
        __syncthreads();
        if (w[2 * threadIdx.x + 1] != 0u) atomicOr(&any_nz, 1);  // first 2KB only
        zcnt[threadIdx.x]       = 0;
        zcnt[threadIdx.x + 256] = 0;
        zcnt[threadIdx.x + 512] = 0;
        zcnt[threadIdx.x + 768] = 0;
        __syncthreads();
        if (threadIdx.x == 0) *flag = (any_nz == 0) ? 1 : 0;
    } else {
        int i = (blockIdx.x - 1) * 256 + threadIdx.x;
        if (i < FEAT * FEAT) {
            o[i]         = (__bf16)a[i];
            o[4096 + i]  = (__bf16)b[i];
            o[8192 + i]  = (__bf16)c[i];
            o[12288 + i] = (__bf16)d[i];
        }
    }
}

// T3-path detect (kept).
__global__ void detect_idx_kernel(const unsigned* __restrict__ w, int* __restrict__ flag,
                                  int* __restrict__ zcnt) {
    __shared__ int any_nz;
    if (threadIdx.x == 0) any_nz = 0;
    __syncthreads();
    if (w[2 * threadIdx.x + 1] != 0u) atomicOr(&any_nz, 1);
    zcnt[threadIdx.x] = 0;
    zcnt[threadIdx.x + 256] = 0;
    __syncthreads();
    if (threadIdx.x == 0) *flag = (any_nz == 0) ? 1 : 0;
}

// 4-byte index load: node ids are < 2^17, so for int64 input the high dword
// is always zero (sniffer-verified) -> read only the low dword.
__device__ __forceinline__ int load_idx_clamped(const void* ei, long long i, int is64, int n_nodes) {
    int v = is64 ? ((const int*)ei)[2 * i] : ((const int*)ei)[i];
    v = v < 0 ? 0 : v;
    return v >= n_nodes ? n_nodes - 1 : v;   // identity when data is sane
}

// ---------------------------------------------------------------------------
// R5 T1 chain: counting sort into 128-node buckets (<=1024 buckets;
// n_nodes <= 131072 guarded at launch). Pack: (d&127)<<17 | s  (24 bits).
// csr_build2 is GONE: the fused edge-centric kernels consume B directly.
// ---------------------------------------------------------------------------

// bucket_count + cast_x fused. Blocks <512 do the LDS-hist count path
// (grid-stride fixed at 512*256); blocks >=512 cast x->bf16.
__global__ __launch_bounds__(256)
void bucket_count_castx_kernel(const void* __restrict__ ei, const int* __restrict__ flagp,
                               int* __restrict__ gcnt,
                               const float* __restrict__ x, __bf16* __restrict__ xb, int n4,
                               int n_edges, int n_nodes) {
    __shared__ int cnt[1024];
    const int t = threadIdx.x;
    if (blockIdx.x < 512) {
        cnt[t] = 0; cnt[t + 256] = 0; cnt[t + 512] = 0; cnt[t + 768] = 0;
        __syncthreads();
        const int is64 = *flagp;
        for (int e = blockIdx.x * 256 + t; e < n_edges; e += 512 * 256) {
            int d = load_idx_clamped(ei, (long long)n_edges + e, is64, n_nodes);
            atomicAdd(&cnt[d >> 7], 1);
        }
        __syncthreads();
        if (cnt[t])       atomicAdd(&gcnt[t], cnt[t]);
        if (cnt[t + 256]) atomicAdd(&gcnt[t + 256], cnt[t + 256]);
        if (cnt[t + 512]) atomicAdd(&gcnt[t + 512], cnt[t + 512]);
        if (cnt[t + 768]) atomicAdd(&gcnt[t + 768], cnt[t + 768]);
    } else {
        const int nb = gridDim.x - 512;
        for (int i = (blockIdx.x - 512) * 256 + t; i < n4; i += nb * 256) {
            float4 v = ((const float4*)x)[i];
            bf16x4 o;
            o.x = (__bf16)v.x; o.y = (__bf16)v.y; o.z = (__bf16)v.z; o.w = (__bf16)v.w;
            ((bf16x4*)xb)[i] = o;
        }
    }
}

// exclusive scan of 1024 bucket counts (512 threads, 2 elems each).
__global__ void bucket_scan_kernel(const int* __restrict__ gcnt, int* __restrict__ gbase,
                                   int* __restrict__ gcur, int n_edges) {
    __shared__ int sh[1024];
    int t = threadIdx.x;
    int v0 = gcnt[t], v1 = gcnt[t + 512];
    sh[t] = v0; sh[t + 512] = v1;
    __syncthreads();
    for (int off = 1; off < 1024; off <<= 1) {
        int u0 = (t >= off) ? sh[t - off] : 0;
        int u1 = (t + 512 >= off) ? sh[t + 512 - off] : 0;
        __syncthreads();
        sh[t] += u0; sh[t + 512] += u1;
        __syncthreads();
    }
    gbase[t]       = sh[t] - v0;       gcur[t]       = sh[t] - v0;
    gbase[t + 512] = sh[t + 512] - v1; gcur[t + 512] = sh[t + 512] - v1;
    if (t == 511) gbase[1024] = n_edges;
}

// multisplit into 1024 buckets; tile of 4096 edges staged in LDS; one global
// atomic per (tile,bucket) reserves a contiguous range.
__global__ __launch_bounds__(256)
void multisplit_kernel(const void* __restrict__ ei, const int* __restrict__ flagp,
                       int* __restrict__ gcur, unsigned* __restrict__ B,
                       int n_edges, int n_nodes) {
    __shared__ unsigned sv[4096];
    __shared__ unsigned dv[4096];
    __shared__ int cnt[1024];
    __shared__ int cur[1024];
    const int t = threadIdx.x;
    const int is64 = *flagp;
    const int ntiles = (n_edges + 4095) >> 12;
    for (int tile = blockIdx.x; tile < ntiles; tile += gridDim.x) {
        cnt[t] = 0; cnt[t + 256] = 0; cnt[t + 512] = 0; cnt[t + 768] = 0;
        __syncthreads();
        #pragma unroll
        for (int k = 0; k < 16; ++k) {
            int i = k * 256 + t;
            int e = (tile << 12) + i;
            unsigned dmark = 0xFFFFFFFFu, s = 0;
            if (e < n_edges) {
                s     = (unsigned)load_idx_clamped(ei, e, is64, n_nodes);
                int d = load_idx_clamped(ei, (long long)n_edges + e, is64, n_nodes);
                dmark = (unsigned)d;
                atomicAdd(&cnt[d >> 7], 1);
            }
            sv[i] = s; dv[i] = dmark;
        }
        __syncthreads();
        if (cnt[t])       cur[t]       = atomicAdd(&gcur[t], cnt[t]);
        if (cnt[t + 256]) cur[t + 256] = atomicAdd(&gcur[t + 256], cnt[t + 256]);
        if (cnt[t + 512]) cur[t + 512] = atomicAdd(&gcur[t + 512], cnt[t + 512]);
        if (cnt[t + 768]) cur[t + 768] = atomicAdd(&gcur[t + 768], cnt[t + 768]);
        __syncthreads();
        #pragma unroll
        for (int k = 0; k < 16; ++k) {
            int i = k * 256 + t;
            unsigned d = dv[i];
            if (d != 0xFFFFFFFFu) {
                int pos = atomicAdd(&cur[d >> 7], 1);
                pos = pos < 0 ? 0 : (pos >= n_edges ? n_edges - 1 : pos);
                B[pos] = ((d & 127u) << 17) | sv[i];
            }
        }
        __syncthreads();
    }
}

// ---------------------------------------------------------------------------
// R5: EDGE-CENTRIC fused layer kernels. One block per 128-node bucket:
//  1) stream the bucket's edges from B (contiguous), per edge: fetch the
//     128B src row (same L2-miss traffic as the old csr gather) and
//     atomicAdd 64 features into accum[128][65] f32 (stride-65 => bank =
//     (dloc+f)%32, near-conflict-free); LDS hist gives deg.
//  2) dinv + convert to bf16 tile sA[128][72].
//  3) proven MFMA epilogue (8 row-tiles; wave w = col-tile w).
// Kills csr_build2 + degc/offs/dinv entirely. ds_add pipe (~1 instr/edge)
// hides under the VMEM miss floor.
// ---------------------------------------------------------------------------
__global__ __launch_bounds__(256)
void fusedE_l1_kernel(const __bf16* __restrict__ xb,
                      const unsigned* __restrict__ B, const int* __restrict__ gbase,
                      const __bf16* __restrict__ Bl, const __bf16* __restrict__ Br,
                      const float* __restrict__ bias,
                      __bf16* __restrict__ hout, int n_nodes) {
    __shared__ float accum[BK * 65];
    __shared__ __align__(16) __bf16 sA[BK][72];
    __shared__ int   cntL[BK];
    __shared__ float dinvL[BK];
    const int t = threadIdx.x, lane = t & 63, wave = t >> 6;
    const int quad = lane >> 4, r16 = lane & 15;
    for (int i = t; i < BK * 65; i += 256) accum[i] = 0.f;
    if (t < BK) cntL[t] = 0;
    bf16x8 bl[2], br[2];
    #pragma unroll
    for (int ks = 0; ks < 2; ++ks) {
        int f = wave * 16 + r16, k = ks * 32 + quad * 8;
        bl[ks] = *(const bf16x8*)(Bl + f * 64 + k);
        br[ks] = *(const bf16x8*)(Br + f * 64 + k);
    }
    const float bv = bias[wave * 16 + r16];
    const int b = blockIdx.x;
    const int lo = gbase[b], hi = gbase[b + 1];
    __syncthreads();
    for (int i = lo + t; i < hi; i += 256) {
        unsigned v = B[i];
        int dloc = v >> 17;
        int s = v & 0x1FFFF;
        s = s >= n_nodes ? n_nodes - 1 : s;
        atomicAdd(&cntL[dloc], 1);
        const bf16x8* rp = (const bf16x8*)xb + (size_t)s * 8;
        float* arow = accum + dloc * 65;
        #pragma unroll
        for (int j = 0; j < 8; ++j) {
            bf16x8 r = rp[j];
            #pragma unroll
            for (int k = 0; k < 8; ++k)
                atomicAdd(arow + j * 8 + k, (float)r[k]);
        }
    }
    __syncthreads();
    if (t < BK) dinvL[t] = 1.0f / fmaxf((float)cntL[t], 1.0f);
    __syncthreads();
    for (int i = t; i < BK * 64; i += 256) {
        int r = i >> 6, f = i & 63;
        sA[r][f] = (__bf16)(accum[r * 65 + f] * dinvL[r]);
    }
    __syncthreads();
    const int m0g = b * BK;
    #pragma unroll
    for (int rt = 0; rt < BK / 16; ++rt) {
        int m0 = m0g + rt * 16;
        if (m0 >= n_nodes) break;
        int mrow = m0 + r16; if (mrow >= n_nodes) mrow = n_nodes - 1;
        bf16x8 ag[2], ax[2];
        #pragma unroll
        for (int ks = 0; ks < 2; ++ks) {
            ag[ks] = *(const bf16x8*)(&sA[rt * 16 + r16][ks * 32 + quad * 8]);
            ax[ks] = *(const bf16x8*)(xb + (size_t)mrow * 64 + ks * 32 + quad * 8);
        }
        f32x4 acc = {0.f, 0.f, 0.f, 0.f};
        acc = __builtin_amdgcn_mfma_f32_16x16x32_bf16(ag[0], bl[0], acc, 0, 0, 0);
        acc = __builtin_amdgcn_mfma_f32_16x16x32_bf16(ag[1], bl[1], acc, 0, 0, 0);
        acc = __builtin_amdgcn_mfma_f32_16x16x32_bf16(ax[0], br[0], acc, 0, 0, 0);
        acc = __builtin_amdgcn_mfma_f32_16x16x32_bf16(ax[1], br[1], acc, 0, 0, 0);
        const int col = wave * 16 + r16;
        #pragma unroll
        for (int rg = 0; rg < 4; ++rg) {
            int row = m0 + quad * 4 + rg;
            if (row < n_nodes) {
                float ov = acc[rg] + bv;
                hout[(size_t)row * 64 + col] = (__bf16)fmaxf(ov, 0.f);
            }
        }
    }
}

__global__ __launch_bounds__(256)
void fusedE_l2_kernel(const __bf16* __restrict__ hb,
                      const unsigned* __restrict__ B, const int* __restrict__ gbase,
                      const __bf16* __restrict__ Bl, const __bf16* __restrict__ Br,
                      const float* __restrict__ bias,
                      float* __restrict__ out, int n_nodes) {
    __shared__ float accum[BK * 65];
    __shared__ __align__(16) __bf16 sA[BK][72];
    __shared__ int   cntL[BK];
    __shared__ float dinvL[BK];
    const int t = threadIdx.x, lane = t & 63, wave = t >> 6;
    const int quad = lane >> 4, r16 = lane & 15;
    for (int i = t; i < BK * 65; i += 256) accum[i] = 0.f;
    if (t < BK) cntL[t] = 0;
    bf16x8 bl[2], br[2];
    #pragma unroll
    for (int ks = 0; ks < 2; ++ks) {
        int f = wave * 16 + r16, k = ks * 32 + quad * 8;
        bl[ks] = *(const bf16x8*)(Bl + f * 64 + k);
        br[ks] = *(const bf16x8*)(Br + f * 64 + k);
    }
    const float bv = bias[wave * 16 + r16];
    const int b = blockIdx.x;
    const int lo = gbase[b], hi = gbase[b + 1];
    __syncthreads();
    for (int i = lo + t; i < hi; i += 256) {
        unsigned v = B[i];
        int dloc = v >> 17;
        int s = v & 0x1FFFF;
        s = s >= n_nodes ? n_nodes - 1 : s;
        atomicAdd(&cntL[dloc], 1);
        const bf16x8* rp = (const bf16x8*)hb + (size_t)s * 8;
        float* arow = accum + dloc * 65;
        #pragma unroll
        for (int j = 0; j < 8; ++j) {
            bf16x8 r = rp[j];
            #pragma unroll
            for (int k = 0; k < 8; ++k)
                atomicAdd(arow + j * 8 + k, (float)r[k]);
        }
    }
    __syncthreads();
    if (t < BK) dinvL[t] = 1.0f / fmaxf((float)cntL[t], 1.0f);
    __syncthreads();
    for (int i = t; i < BK * 64; i += 256) {
        int r = i >> 6, f = i & 63;
        sA[r][f] = (__bf16)(accum[r * 65 + f] * dinvL[r]);
    }
    __syncthreads();
    const int m0g = b * BK;
    #pragma unroll
    for (int rt = 0; rt < BK / 16; ++rt) {
        int m0 = m0g + rt * 16;
        if (m0 >= n_nodes) break;
        int mrow = m0 + r16; if (mrow >= n_nodes) mrow = n_nodes - 1;
        bf16x8 ag[2], ah[2];
        #pragma unroll
        for (int ks = 0; ks < 2; ++ks) {
            ag[ks] = *(const bf16x8*)(&sA[rt * 16 + r16][ks * 32 + quad * 8]);
            ah[ks] = *(const bf16x8*)(hb + (size_t)mrow * 64 + ks * 32 + quad * 8);
        }
        f32x4 acc = {0.f, 0.f, 0.f, 0.f};
        acc = __builtin_amdgcn_mfma_f32_16x16x32_bf16(ag[0], bl[0], acc, 0, 0, 0);
        acc = __builtin_amdgcn_mfma_f32_16x16x32_bf16(ag[1], bl[1], acc, 0, 0, 0);
        acc = __builtin_amdgcn_mfma_f32_16x16x32_bf16(ah[0], br[0], acc, 0, 0, 0);
        acc = __builtin_amdgcn_mfma_f32_16x16x32_bf16(ah[1], br[1], acc, 0, 0, 0);
        const int col = wave * 16 + r16;
        #pragma unroll
        for (int rg = 0; rg < 4; ++rg) {
            int row = m0 + quad * 4 + rg;
            if (row < n_nodes) out[(size_t)row * 64 + col] = acc[rg] + bv;
        }
    }
}

// ---------------------------------------------------------------------------
// Scans (T3/T4 paths)
// ---------------------------------------------------------------------------
__global__ __launch_bounds__(256)
void scan_partial_kernel(const int* __restrict__ degc, int* __restrict__ part, int n_nodes) {
    __shared__ int sh[256];
    int i = blockIdx.x * 256 + threadIdx.x;
    sh[threadIdx.x] = (i < n_nodes) ? degc[i] : 0;
    __syncthreads();
    for (int off = 128; off > 0; off >>= 1) {
        if (threadIdx.x < off) sh[threadIdx.x] += sh[threadIdx.x + off];
        __syncthreads();
    }
    if (threadIdx.x == 0) part[blockIdx.x] = sh[0];
}

__global__ void scan_top_kernel(int* __restrict__ part, int nparts) {
    __shared__ int sh[512];
    int t = threadIdx.x;
    int v = (t < nparts) ? part[t] : 0;
    sh[t] = v;
    __syncthreads();
    for (int off = 1; off < 512; off <<= 1) {
        int u = (t >= off) ? sh[t - off] : 0;
        __syncthreads();
        sh[t] += u;
        __syncthreads();
    }
    if (t < nparts) part[t] = sh[t] - v;   // exclusive
}

__global__ __launch_bounds__(256)
void scan_final_kernel(const int* __restrict__ degc, const int* __restrict__ part,
                       int* __restrict__ offs, float* __restrict__ deg_inv, int n_nodes) {
    __shared__ int sh[256];
    int t = threadIdx.x;
    int i = blockIdx.x * 256 + t;
    int v = (i < n_nodes) ? degc[i] : 0;
    sh[t] = v;
    __syncthreads();
    for (int off = 1; off < 256; off <<= 1) {
        int u = (t >= off) ? sh[t - off] : 0;
        __syncthreads();
        sh[t] += u;
        __syncthreads();
    }
    if (i < n_nodes) {
        offs[i]    = sh[t] - v + part[blockIdx.x];
        deg_inv[i] = 1.0f / fmaxf((float)v, 1.0f);
    }
}

// ---------------------------------------------------------------------------
// T3 path: global-atomic hist + cursor scatter.
// ---------------------------------------------------------------------------
__global__ __launch_bounds__(256)
void hist_kernel(const void* __restrict__ ei, const int* __restrict__ flagp,
                 int* __restrict__ degc, int n_edges, int n_nodes) {
    int e = blockIdx.x * 256 + threadIdx.x;
    if (e >= n_edges) return;
    int d = load_idx_clamped(ei, (long long)n_edges + e, *flagp, n_nodes);
    atomicAdd(&degc[d], 1);
}

__global__ __launch_bounds__(256)
void csr_scatter_kernel(const void* __restrict__ ei, const int* __restrict__ flagp,
                        const int* __restrict__ offs, int* __restrict__ cursor,
                        int* __restrict__ csr, int n_edges, int n_nodes) {
    int e = blockIdx.x * 256 + threadIdx.x;
    if (e >= n_edges) return;
    int is64 = *flagp;
    int s = load_idx_clamped(ei, e, is64, n_nodes);
    int d = load_idx_clamped(ei, (long long)n_edges + e, is64, n_nodes);
    int pos = offs[d] + atomicAdd(&cursor[d], 1);
    pos = pos < 0 ? 0 : (pos >= n_edges ? n_edges - 1 : pos);
    csr[pos] = s;
}

// ---------------------------------------------------------------------------
// Casts (T3 fallback path)
// ---------------------------------------------------------------------------
__global__ __launch_bounds__(256)
void cast_w_kernel(const float* __restrict__ a, const float* __restrict__ b,
                   const float* __restrict__ c, const float* __restrict__ d,
                   __bf16* __restrict__ o) {
    int i = blockIdx.x * 256 + threadIdx.x;
    if (i < FEAT * FEAT) {
        o[i]         = (__bf16)a[i];
        o[4096 + i]  = (__bf16)b[i];
        o[8192 + i]  = (__bf16)c[i];
        o[12288 + i] = (__bf16)d[i];
    }
}

// ---------------------------------------------------------------------------
// Standalone gather kernels (T3 fallback path; unchanged, proven).
// ---------------------------------------------------------------------------
__global__ __launch_bounds__(256)
void gather_bf16_kernel(const __bf16* __restrict__ hin, const int* __restrict__ offs,
                        const int* __restrict__ degc, const float* __restrict__ dinv,
                        const int* __restrict__ csr, __bf16* __restrict__ agg,
                        int n_nodes) {
    const int t = threadIdx.x, u = t & 15;
    const int g0 = blockIdx.x * 16 + (t >> 4);
    const int ng = gridDim.x * 16;
    if (g0 >= n_nodes) return;
    int rs = offs[g0], cnt = degc[g0];
    float di = dinv[g0];
    int idx = (u < cnt) ? (int)__builtin_nontemporal_load(&csr[rs + u]) : 0;
    for (int n = g0; n < n_nodes; n += ng) {
        const int nn = n + ng;
        int rs2 = 0, cnt2 = 0;
        float di2 = 1.0f;
        if (nn < n_nodes) { rs2 = offs[nn]; cnt2 = degc[nn]; di2 = dinv[nn]; }
        float a0 = 0.f, a1 = 0.f, a2 = 0.f, a3 = 0.f;
        int c = 0;
        while (true) {
            idx = idx < 0 ? 0 : (idx >= n_nodes ? n_nodes - 1 : idx);
            int sj[16];
            #pragma unroll
            for (int j = 0; j < 16; ++j) sj[j] = __shfl(idx, j, 16);
            bf16x4 v[16];
            #pragma unroll
            for (int j = 0; j < 16; ++j)
                v[j] = ((const bf16x4*)hin)[(size_t)sj[j] * 16 + u];
            #pragma unroll
            for (int j = 0; j < 16; ++j) {
                float m = (c + j < cnt) ? 1.f : 0.f;
                a0 = fmaf(m, (float)v[j].x, a0);
                a1 = fmaf(m, (float)v[j].y, a1);
                a2 = fmaf(m, (float)v[j].z, a2);
                a3 = fmaf(m, (float)v[j].w, a3);
            }
            c += 16;
            if (c >= cnt) break;
            idx = (u < cnt - c) ? (int)__builtin_nontemporal_load(&csr[rs + c + u]) : 0;
        }
        idx = (nn < n_nodes && u < cnt2)
                  ? (int)__builtin_nontemporal_load(&csr[rs2 + u]) : 0;
        bf16x4 o;
        o.x = (__bf16)(a0 * di); o.y = (__bf16)(a1 * di);
        o.z = (__bf16)(a2 * di); o.w = (__bf16)(a3 * di);
        ((bf16x4*)agg)[(size_t)n * 16 + u] = o;
        rs = rs2; cnt = cnt2; di = di2;
    }
}

__global__ __launch_bounds__(256)
void gather_f32_kernel(const float* __restrict__ xin, const int* __restrict__ offs,
                       const int* __restrict__ degc, const float* __restrict__ dinv,
                       const int* __restrict__ csr, __bf16* __restrict__ agg,
                       int n_nodes) {
    const int t = threadIdx.x, lane = t & 63, g = lane >> 4, u = lane & 15;
    const int gw = blockIdx.x * 4 + (t >> 6), nw = gridDim.x * 4;
    for (int n = gw; n < n_nodes; n += nw) {
        int rs = offs[n], cnt = degc[n];
        float a0 = 0.f, a1 = 0.f, a2 = 0.f, a3 = 0.f;
        for (int c = 0; c < cnt; c += 64) {
            int chunk = min(64, cnt - c);
            int myid = (lane < chunk) ? (int)__builtin_nontemporal_load(&csr[rs + c + lane]) : 0;
            myid = myid < 0 ? 0 : (myid >= n_nodes ? n_nodes - 1 : myid);
            for (int q = 0; q < chunk; q += 16) {
                int q0 = q + g, q1 = q + g + 4, q2 = q + g + 8, q3 = q + g + 12;
                int s0 = __shfl(myid, q0), s1 = __shfl(myid, q1);
                int s2 = __shfl(myid, q2), s3 = __shfl(myid, q3);
                float m0 = (q0 < chunk) ? 1.f : 0.f;
                float m1 = (q1 < chunk) ? 1.f : 0.f;
                float m2 = (q2 < chunk) ? 1.f : 0.f;
                float m3 = (q3 < chunk) ? 1.f : 0.f;
                float4 v0 = ((const float4*)xin)[(size_t)s0 * 16 + u];
                float4 v1 = ((const float4*)xin)[(size_t)s1 * 16 + u];
                float4 v2 = ((const float4*)xin)[(size_t)s2 * 16 + u];
                float4 v3 = ((const float4*)xin)[(size_t)s3 * 16 + u];
                a0 = fmaf(m0, v0.x, a0); a1 = fmaf(m0, v0.y, a1);
                a2 = fmaf(m0, v0.z, a2); a3 = fmaf(m0, v0.w, a3);
                a0 = fmaf(m1, v1.x, a0); a1 = fmaf(m1, v1.y, a1);
                a2 = fmaf(m1, v1.z, a2); a3 = fmaf(m1, v1.w, a3);
                a0 = fmaf(m2, v2.x, a0); a1 = fmaf(m2, v2.y, a1);
                a2 = fmaf(m2, v2.z, a2); a3 = fmaf(m2, v2.w, a3);
                a0 = fmaf(m3, v3.x, a0); a1 = fmaf(m3, v3.y, a1);
                a2 = fmaf(m3, v3.z, a2); a3 = fmaf(m3, v3.w, a3);
            }
        }
        a0 += __shfl_xor(a0, 16); a1 += __shfl_xor(a1, 16);
        a2 += __shfl_xor(a2, 16); a3 += __shfl_xor(a3, 16);
        a0 += __shfl_xor(a0, 32); a1 += __shfl_xor(a1, 32);
        a2 += __shfl_xor(a2, 32); a3 += __shfl_xor(a3, 32);
        if (g == 0) {
            float di = dinv[n];
            bf16x4 o;
            o.x = (__bf16)(a0 * di); o.y = (__bf16)(a1 * di);
            o.z = (__bf16)(a2 * di); o.w = (__bf16)(a3 * di);
            ((bf16x4*)agg)[(size_t)n * 16 + u] = o;
        }
    }
}

// ---------------------------------------------------------------------------
// Standalone MFMA GEMMs (T3 fallback path; unchanged, proven).
// ---------------------------------------------------------------------------
__global__ __launch_bounds__(256)
void gemm_l1_kernel(const __bf16* __restrict__ Ag, const float* __restrict__ xin,
                    const __bf16* __restrict__ Bl, const __bf16* __restrict__ Br,
                    const float* __restrict__ bias,
                    __bf16* __restrict__ hout, int n_nodes) {
    const int t = threadIdx.x, lane = t & 63;
    const int quad = lane >> 4, r16 = lane & 15;
    bf16x8 bl[2][4], br[2][4];
    #pragma unroll
    for (int ks = 0; ks < 2; ++ks)
        #pragma unroll
        for (int ct = 0; ct < 4; ++ct) {
            int f = ct * 16 + r16, k = ks * 32 + quad * 8;
            bl[ks][ct] = *(const bf16x8*)(Bl + f * 64 + k);
            br[ks][ct] = *(const bf16x8*)(Br + f * 64 + k);
        }
    const int m0 = (blockIdx.x * 4 + (t >> 6)) * 16;
    if (m0 >= n_nodes) return;
    int mrow = m0 + r16; if (mrow >= n_nodes) mrow = n_nodes - 1;
    bf16x8 ag[2], ax[2];
    #pragma unroll
    for (int ks = 0; ks < 2; ++ks) {
        ag[ks] = *(const bf16x8*)(Ag + (size_t)mrow * 64 + ks * 32 + quad * 8);
        const float* xr = xin + (size_t)mrow * 64 + ks * 32 + quad * 8;
        float4 p = *(const float4*)xr;
        float4 q = *(const float4*)(xr + 4);
        union { bf16x8 v; __bf16 e[8]; } U;
        U.e[0] = (__bf16)p.x; U.e[1] = (__bf16)p.y; U.e[2] = (__bf16)p.z; U.e[3] = (__bf16)p.w;
        U.e[4] = (__bf16)q.x; U.e[5] = (__bf16)q.y; U.e[6] = (__bf16)q.z; U.e[7] = (__bf16)q.w;
        ax[ks] = U.v;
    }
    #pragma unroll
    for (int ct = 0; ct < 4; ++ct) {
        f32x4 acc = {0.f, 0.f, 0.f, 0.f};
        acc = __builtin_amdgcn_mfma_f32_16x16x32_bf16(ag[0], bl[0][ct], acc, 0, 0, 0);
        acc = __builtin_amdgcn_mfma_f32_16x16x32_bf16(ag[1], bl[1][ct], acc, 0, 0, 0);
        acc = __builtin_amdgcn_mfma_f32_16x16x32_bf16(ax[0], br[0][ct], acc, 0, 0, 0);
        acc = __builtin_amdgcn_mfma_f32_16x16x32_bf16(ax[1], br[1][ct], acc, 0, 0, 0);
        int col = ct * 16 + r16;
        float bv = bias[col];
        #pragma unroll
        for (int rg = 0; rg < 4; ++rg) {
            int n = m0 + quad * 4 + rg;
            if (n < n_nodes) {
                float o = acc[rg] + bv;
                hout[(size_t)n * 64 + col] = (__bf16)fmaxf(o, 0.f);
            }
        }
    }
}

__global__ __launch_bounds__(256)
void gemm_l2_kernel(const __bf16* __restrict__ Ag, const __bf16* __restrict__ Ah,
                    const __bf16* __restrict__ Bl, const __bf16* __restrict__ Br,
                    const float* __restrict__ bias,
                    float* __restrict__ out, int n_nodes) {
    const int t = threadIdx.x, lane = t & 63;
    const int quad = lane >> 4, r16 = lane & 15;
    bf16x8 bl[2][4], br[2][4];
    #pragma unroll
    for (int ks = 0; ks < 2; ++ks)
        #pragma unroll
        for (int ct = 0; ct < 4; ++ct) {
            int f = ct * 16 + r16, k = ks * 32 + quad * 8;
            bl[ks][ct] = *(const bf16x8*)(Bl + f * 64 + k);
            br[ks][ct] = *(const bf16x8*)(Br + f * 64 + k);
        }
    const int m0 = (blockIdx.x * 4 + (t >> 6)) * 16;
    if (m0 >= n_nodes) return;
    int mrow = m0 + r16; if (mrow >= n_nodes) mrow = n_nodes - 1;
    bf16x8 ag[2], ah[2];
    #pragma unroll
    for (int ks = 0; ks < 2; ++ks) {
        ag[ks] = *(const bf16x8*)(Ag + (size_t)mrow * 64 + ks * 32 + quad * 8);
        ah[ks] = *(const bf16x8*)(Ah + (size_t)mrow * 64 + ks * 32 + quad * 8);
    }
    #pragma unroll
    for (int ct = 0; ct < 4; ++ct) {
        f32x4 acc = {0.f, 0.f, 0.f, 0.f};
        acc = __builtin_amdgcn_mfma_f32_16x16x32_bf16(ag[0], bl[0][ct], acc, 0, 0, 0);
        acc = __builtin_amdgcn_mfma_f32_16x16x32_bf16(ag[1], bl[1][ct], acc, 0, 0, 0);
        acc = __builtin_amdgcn_mfma_f32_16x16x32_bf16(ah[0], br[0][ct], acc, 0, 0, 0);
        acc = __builtin_amdgcn_mfma_f32_16x16x32_bf16(ah[1], br[1][ct], acc, 0, 0, 0);
        int col = ct * 16 + r16;
        float bv = bias[col];
        #pragma unroll
        for (int rg = 0; rg < 4; ++rg) {
            int n = m0 + quad * 4 + rg;
            if (n < n_nodes) out[(size_t)n * 64 + col] = acc[rg] + bv;
        }
    }
}

// ---------------------------------------------------------------------------
// T4 fallback: fused LDS kernels (unchanged).
// ---------------------------------------------------------------------------
__global__ __launch_bounds__(256)
void sage_fused_l1_kernel(const float* __restrict__ xin,
                          const int* __restrict__ offs, const int* __restrict__ degc,
                          const float* __restrict__ deg_inv, const int* __restrict__ csr,
                          const float* __restrict__ Wl, const float* __restrict__ bias,
                          const float* __restrict__ Wr,
                          __bf16* __restrict__ hout, int n_nodes) {
    __shared__ float WlT[FEAT * 65], WrT[FEAT * 65], bsh[FEAT];
    __shared__ float aggS[4][FEAT], selfS[4][FEAT];
    const int t = threadIdx.x;
    #pragma unroll
    for (int p = 0; p < 16; ++p) {
        int i = t + p * 256, j = i >> 6, k = i & 63;
        WlT[k * 65 + j] = Wl[i];
        WrT[k * 65 + j] = Wr[i];
    }
    if (t < FEAT) bsh[t] = bias[t];
    __syncthreads();
    const int w = t >> 6, f = t & 63;
    const int n_groups = (n_nodes + 3) >> 2;
    for (int g = blockIdx.x; g < n_groups; g += gridDim.x) {
        int n = g * 4 + w;
        bool act = (n < n_nodes);
        if (act) {
            int rs = offs[n], cnt = degc[n];
            float acc = 0.f;
            for (int c = 0; c < cnt; c += 64) {
                int chunk = min(64, cnt - c);
                int myid = (f < chunk) ? csr[rs + c + f] : 0;
                #pragma unroll 4
                for (int q = 0; q < chunk; ++q) {
                    int s = __shfl(myid, q);
                    acc += xin[(long long)s * FEAT + f];
                }
            }
            aggS[w][f]  = acc * deg_inv[n];
            selfS[w][f] = xin[(long long)n * FEAT + f];
        }
        __syncthreads();
        if (act) {
            float o = bsh[f];
            #pragma unroll
            for (int k = 0; k < FEAT; ++k) {
                o = fmaf(aggS[w][k],  WlT[k * 65 + f], o);
                o = fmaf(selfS[w][k], WrT[k * 65 + f], o);
            }
            o = fmaxf(o, 0.f);
            hout[(long long)n * FEAT + f] = (__bf16)o;
        }
        __syncthreads();
    }
}

__global__ __launch_bounds__(256)
void sage_fused_l2_kernel(const __bf16* __restrict__ hin,
                          const int* __restrict__ offs, const int* __restrict__ degc,
                          const float* __restrict__ deg_inv, const int* __restrict__ csr,
                          const float* __restrict__ Wl, const float* __restrict__ bias,
                          const float* __restrict__ Wr,
                          float* __restrict__ out, int n_nodes) {
    __shared__ float WlT[FEAT * 65], WrT[FEAT * 65], bsh[FEAT];
    __shared__ float aggS[4][FEAT], selfS[4][FEAT];
    const int t = threadIdx.x;
    #pragma unroll
    for (int p = 0; p < 16; ++p) {
        int i = t + p * 256, j = i >> 6, k = i & 63;
        WlT[k * 65 + j] = Wl[i];
        WrT[k * 65 + j] = Wr[i];
    }
    if (t < FEAT) bsh[t] = bias[t];
    __syncthreads();
    const int w = t >> 6, f = t & 63;
    const int n_groups = (n_nodes + 3) >> 2;
    for (int g = blockIdx.x; g < n_groups; g += gridDim.x) {
        int n = g * 4 + w;
        bool act = (n < n_nodes);
        if (act) {
            int rs = offs[n], cnt = degc[n];
            float acc = 0.f;
            for (int c = 0; c < cnt; c += 64) {
                int chunk = min(64, cnt - c);
                int myid = (f < chunk) ? csr[rs + c + f] : 0;
                #pragma unroll 4
                for (int q = 0; q < chunk; ++q) {
                    int s = __shfl(myid, q);
                    acc += (float)hin[(long long)s * FEAT + f];
                }
            }
            aggS[w][f]  = acc * deg_inv[n];
            selfS[w][f] = (float)hin[(long long)n * FEAT + f];
        }
        __syncthreads();
        if (act) {
            float o = bsh[f];
            #pragma unroll
            for (int k = 0; k < FEAT; ++k) {
                o = fmaf(aggS[w][k],  WlT[k * 65 + f], o);
                o = fmaf(selfS[w][k], WrT[k * 65 + f], o);
            }
            out[(long long)n * FEAT + f] = o;
        }
        __syncthreads();
    }
}

// ---------------------------------------------------------------------------
// Launch
// ---------------------------------------------------------------------------
extern "C" void kernel_launch(void* const* d_in, const int* in_sizes, int n_in,
                              void* d_out, int out_size, void* d_ws, size_t ws_size,
                              hipStream_t stream) {
    const float* x   = (const float*)d_in[0];
    const void*  ei  = d_in[1];
    const float* W1l = (const float*)d_in[2];
    const float* b1  = (const float*)d_in[3];
    const float* W1r = (const float*)d_in[4];
    const float* W2l = (const float*)d_in[5];
    const float* b2  = (const float*)d_in[6];
    const float* W2r = (const float*)d_in[7];
    float* out = (float*)d_out;

    const int n_nodes = in_sizes[0] / FEAT;
    const int n_edges = in_sizes[1] / 2;
    const int nparts  = (n_nodes + 255) / 256;     // <= 512
    const int egrid   = (n_edges + 255) / 256;
    const int NB128   = (n_nodes + BK - 1) / BK;   // <= 1024

    char* ws = (char*)d_ws;
    auto al = [](size_t v) { return (v + 255) & ~(size_t)255; };

    // ---- T1 layout (edge-centric; csr/degc/offs/dinv removed in R5) ----
    size_t o = 0;
    int*      flag  = (int*)(ws + o);      o += 256;
    int*      gcnt  = (int*)(ws + o);      o += al(1024 * 4);
    int*      gbase = (int*)(ws + o);      o += al(1025 * 4);
    int*      gcur  = (int*)(ws + o);      o += al(1024 * 4);
    unsigned* B     = (unsigned*)(ws + o); o += al((size_t)n_edges * 4);
    __bf16*   xb    = (__bf16*)(ws + o);   o += al((size_t)n_nodes * FEAT * 2);
    __bf16*   wb    = (__bf16*)(ws + o);   o += al((size_t)4 * FEAT * FEAT * 2);
    __bf16*   h     = (__bf16*)(ws + o);   o += al((size_t)n_nodes * FEAT * 2);
    const size_t needT1 = o;

    // ---- T3 layout (proven fallback) ----
    size_t o3 = 0;
    int*    flag3   = (int*)(ws + o3);    o3 += 256;
    int*    degc3   = (int*)(ws + o3);    o3 += al((size_t)n_nodes * 4);
    float*  dinv3   = (float*)(ws + o3);  o3 += al((size_t)n_nodes * 4);
    int*    offs3   = (int*)(ws + o3);    o3 += al((size_t)n_nodes * 4);
    int*    cursor3 = (int*)(ws + o3);    o3 += al((size_t)n_nodes * 4);
    int*    part3   = (int*)(ws + o3);    o3 += al(2048);
    int*    csr3    = (int*)(ws + o3);    o3 += al((size_t)n_edges * 4);
    const size_t commonEnd3 = o3;
    __bf16* wb3  = (__bf16*)(ws + o3);    o3 += al((size_t)4 * FEAT * FEAT * 2);
    __bf16* agg3 = (__bf16*)(ws + o3);    o3 += al((size_t)n_nodes * FEAT * 2);
    __bf16* h3   = (__bf16*)(ws + o3);    o3 += al((size_t)n_nodes * FEAT * 2);
    const size_t needT3 = o3;

    const int n4 = n_nodes * FEAT / 4;
    const int mgrid = (n_nodes + 63) / 64;
    const int ggrid = 2048;
    const int ntiles = (n_edges + 4095) >> 12;

    if (ws_size >= needT1 && n_nodes <= 131072) {
        detect_castw_kernel<<<17, 256, 0, stream>>>((const unsigned*)ei, flag, gcnt,
                                                    W1l, W1r, W2l, W2r, wb);
        bucket_count_castx_kernel<<<1536, 256, 0, stream>>>(ei, flag, gcnt,
                                                            x, xb, n4, n_edges, n_nodes);
        bucket_scan_kernel<<<1, 512, 0, stream>>>(gcnt, gbase, gcur, n_edges);
        multisplit_kernel<<<ntiles, 256, 0, stream>>>(ei, flag, gcur, B, n_edges, n_nodes);
        fusedE_l1_kernel<<<NB128, 256, 0, stream>>>(xb, B, gbase,
                                                    wb, wb + 4096, b1, h, n_nodes);
        fusedE_l2_kernel<<<NB128, 256, 0, stream>>>(h, B, gbase,
                                                    wb + 8192, wb + 12288, b2, out, n_nodes);
    } else if (ws_size >= needT3) {
        zero2_kernel<<<nparts, 256, 0, stream>>>(degc3, cursor3, n_nodes);
        detect_idx_kernel<<<1, 256, 0, stream>>>((const unsigned*)ei, flag3, part3);
        hist_kernel<<<egrid, 256, 0, stream>>>(ei, flag3, degc3, n_edges, n_nodes);
        scan_partial_kernel<<<nparts, 256, 0, stream>>>(degc3, part3, n_nodes);
        scan_top_kernel<<<1, 512, 0, stream>>>(part3, nparts);
        scan_final_kernel<<<nparts, 256, 0, stream>>>(degc3, part3, offs3, dinv3, n_nodes);
        csr_scatter_kernel<<<egrid, 256, 0, stream>>>(ei, flag3, offs3, cursor3, csr3, n_edges, n_nodes);
        cast_w_kernel<<<16, 256, 0, stream>>>(W1l, W1r, W2l, W2r, wb3);
        gather_f32_kernel<<<ggrid, 256, 0, stream>>>(x, offs3, degc3, dinv3, csr3, agg3, n_nodes);
        gemm_l1_kernel<<<mgrid, 256, 0, stream>>>(agg3, x, wb3, wb3 + 4096, b1, h3, n_nodes);
        gather_bf16_kernel<<<ggrid, 256, 0, stream>>>(h3, offs3, degc3, dinv3, csr3, agg3, n_nodes);
        gemm_l2_kernel<<<mgrid, 256, 0, stream>>>(agg3, h3, wb3 + 8192, wb3 + 12288, b2, out, n_nodes);
    } else {
        __bf16* hf = (__bf16*)(ws + commonEnd3);
        zero2_kernel<<<nparts, 256, 0, stream>>>(degc3, cursor3, n_nodes);
        detect_idx_kernel<<<1, 256, 0, stream>>>((const unsigned*)ei, flag3, part3);
        hist_kernel<<<egrid, 256, 0, stream>>>(ei, flag3, degc3, n_edges, n_nodes);
        scan_partial_kernel<<<nparts, 256, 0, stream>>>(degc3, part3, n_nodes);
        scan_top_kernel<<<1, 512, 0, stream>>>(part3, nparts);
        scan_final_kernel<<<nparts, 256, 0, stream>>>(degc3, part3, offs3, dinv3, n_nodes);
        csr_scatter_kernel<<<egrid, 256, 0, stream>>>(ei, flag3, offs3, cursor3, csr3, n_edges, n_nodes);
        const int n_groups = (n_nodes + 3) / 4;
        const int fgrid = n_groups < 4096 ? n_groups : 4096;
        sage_fused_l1_kernel<<<fgrid, 256, 0, stream>>>(x, offs3, degc3, dinv3, csr3,
                                                        W1l, b1, W1r, hf, n_nodes);
        sage_fused_l2_kernel<<<fgrid, 256, 0, stream>>>(hf, offs3, degc3, dinv3, csr3,
                                                        W2l, b2, W2r, out, n_nodes);
    }
}

// Round 7
// 255.403 us; speedup vs baseline: 5.8302x; 5.8302x over previous
//
#include <hip/hip_runtime.h>
#include <hip/hip_bf16.h>

#define FEAT 64

typedef __bf16 bf16x8 __attribute__((ext_vector_type(8)));
typedef __bf16 bf16x4 __attribute__((ext_vector_type(4)));
typedef float  f32x4  __attribute__((ext_vector_type(4)));

// ---------------------------------------------------------------------------
// R5 POST-MORTEM (kept as a warning): edge-centric LDS-atomicAdd aggregation
// (fusedE) ran 685us/layer, VALUBusy 0.97% -- 64 serialized ds_add per edge
// per THREAD starves the memory pipe. Per-node csr gather (R4) is the proven
// structure; R6 reverts to it and trims the CSR-build chain instead.
// R6 bench never executed (container acquisition failed twice) -> resubmit
// unchanged to get the measurement.
// ---------------------------------------------------------------------------

// ---------------------------------------------------------------------------
// Zero kernel (hipMemsetAsync may execute at capture time -> poisoned replay).
// ---------------------------------------------------------------------------
__global__ __launch_bounds__(256)
void zero2_kernel(int* __restrict__ a, int* __restrict__ b, int n) {
    int i = blockIdx.x * 256 + threadIdx.x;
    if (i < n) { a[i] = 0; b[i] = 0; }
}

// ---------------------------------------------------------------------------
// detect + cast_w fused (block 0 sniffs int64-ness & zeroes the 512-entry
// bucket counter array + the scan ticket; blocks 1..16 cast the 4 weights).
// ---------------------------------------------------------------------------
__global__ void detect_castw_kernel(const unsigned* __restrict__ w, int* __restrict__ flag,
                                    int* __restrict__ zcnt,
                                    const float* __restrict__ a, const float* __restrict__ b,
                                    const float* __restrict__ c, const float* __restrict__ d,
                                    __bf16* __restrict__ o) {
    if (blockIdx.x == 0) {
        __shared__ int any_nz;
        if (threadIdx.x == 0) any_nz = 0;
        __syncthreads();
        if (w[2 * threadIdx.x + 1] != 0u) atomicOr(&any_nz, 1);  // first 2KB only
        zcnt[threadIdx.x]       = 0;
        zcnt[threadIdx.x + 256] = 0;
        if (threadIdx.x == 0) zcnt[512] = 0;   // scan ticket
        __syncthreads();
        if (threadIdx.x == 0) *flag = (any_nz == 0) ? 1 : 0;
    } else {
        int i = (blockIdx.x - 1) * 256 + threadIdx.x;
        if (i < FEAT * FEAT) {
            o[i]         = (__bf16)a[i];
            o[4096 + i]  = (__bf16)b[i];
            o[8192 + i]  = (__bf16)c[i];
            o[12288 + i] = (__bf16)d[i];
        }
    }
}

// T3-path detect (kept).
__global__ void detect_idx_kernel(const unsigned* __restrict__ w, int* __restrict__ flag,
                                  int* __restrict__ zcnt) {
    __shared__ int any_nz;
    if (threadIdx.x == 0) any_nz = 0;
    __syncthreads();
    if (w[2 * threadIdx.x + 1] != 0u) atomicOr(&any_nz, 1);
    zcnt[threadIdx.x] = 0;
    zcnt[threadIdx.x + 256] = 0;
    __syncthreads();
    if (threadIdx.x == 0) *flag = (any_nz == 0) ? 1 : 0;
}

// 4-byte index load: node ids are < 2^17, so for int64 input the high dword
// is always zero (sniffer-verified) -> read only the low dword.
__device__ __forceinline__ int load_idx_clamped(const void* ei, long long i, int is64, int n_nodes) {
    int v = is64 ? ((const int*)ei)[2 * i] : ((const int*)ei)[i];
    v = v < 0 ? 0 : v;
    return v >= n_nodes ? n_nodes - 1 : v;   // identity when data is sane
}

// ---------------------------------------------------------------------------
// T1 CSR build == two-level counting sort, bucket = dst>>8 (256 nodes/bucket,
// <=512 buckets; n_nodes <= 131072 guarded at launch).
// Pack: (d&255)<<17 | s  (25 bits).
// R6: bucket_scan folded into bucket_count (last-block ticket); csr_build2
// at 256-node buckets -> 391 blocks (was 196), halved per-block serial work.
// ---------------------------------------------------------------------------

// bucket_count + cast_x fused + in-kernel scan. Blocks <512 do the LDS-hist
// count path (grid-stride fixed at 512*256); blocks >=512 cast x->bf16.
// The LAST count block to finish performs the 512-entry exclusive scan into
// gbase/gcur (gcnt read back via atomicAdd(p,0) -> coherent, bypasses L1).
__global__ __launch_bounds__(256)
void bucket_count_castx_kernel(const void* __restrict__ ei, const int* __restrict__ flagp,
                               int* __restrict__ gcnt, int* __restrict__ gbase,
                               int* __restrict__ gcur,
                               const float* __restrict__ x, __bf16* __restrict__ xb, int n4,
                               int n_edges, int n_nodes) {
    __shared__ int cnt[512];
    __shared__ int amLast;
    const int t = threadIdx.x;
    if (blockIdx.x < 512) {
        cnt[t] = 0; cnt[t + 256] = 0;
        __syncthreads();
        const int is64 = *flagp;
        for (int e = blockIdx.x * 256 + t; e < n_edges; e += 512 * 256) {
            int d = load_idx_clamped(ei, (long long)n_edges + e, is64, n_nodes);
            atomicAdd(&cnt[d >> 8], 1);
        }
        __syncthreads();
        if (cnt[t])       atomicAdd(&gcnt[t], cnt[t]);
        if (cnt[t + 256]) atomicAdd(&gcnt[t + 256], cnt[t + 256]);
        // ---- last-block scan (replaces bucket_scan_kernel) ----
        __threadfence();
        __syncthreads();
        if (t == 0) amLast = (atomicAdd(&gcnt[512], 1) == 511);
        __syncthreads();
        if (amLast) {
            __shared__ int scn[512];
            int v0 = atomicAdd(&gcnt[t], 0);          // coherent read
            int v1 = atomicAdd(&gcnt[t + 256], 0);
            scn[t] = v0; scn[t + 256] = v1;
            __syncthreads();
            for (int off = 1; off < 512; off <<= 1) {
                int u0 = (t >= off) ? scn[t - off] : 0;
                int u1 = (t + 256 >= off) ? scn[t + 256 - off] : 0;
                __syncthreads();
                scn[t] += u0; scn[t + 256] += u1;
                __syncthreads();
            }
            gbase[t]       = scn[t] - v0;       gcur[t]       = scn[t] - v0;
            gbase[t + 256] = scn[t + 256] - v1; gcur[t + 256] = scn[t + 256] - v1;
            if (t == 0) gbase[512] = n_edges;
        }
    } else {
        const int nb = gridDim.x - 512;
        for (int i = (blockIdx.x - 512) * 256 + t; i < n4; i += nb * 256) {
            float4 v = ((const float4*)x)[i];
            bf16x4 o;
            o.x = (__bf16)v.x; o.y = (__bf16)v.y; o.z = (__bf16)v.z; o.w = (__bf16)v.w;
            ((bf16x4*)xb)[i] = o;
        }
    }
}

// multisplit into 256-node buckets; tile of 4096 edges staged in LDS; one
// global atomic per (tile,bucket) reserves a contiguous range.
__global__ __launch_bounds__(256)
void multisplit_kernel(const void* __restrict__ ei, const int* __restrict__ flagp,
                       int* __restrict__ gcur, unsigned* __restrict__ B,
                       int n_edges, int n_nodes) {
    __shared__ unsigned sv[4096];
    __shared__ unsigned dv[4096];
    __shared__ int cnt[512];
    __shared__ int cur[512];
    const int t = threadIdx.x;
    const int is64 = *flagp;
    const int ntiles = (n_edges + 4095) >> 12;
    for (int tile = blockIdx.x; tile < ntiles; tile += gridDim.x) {
        cnt[t] = 0; cnt[t + 256] = 0;
        __syncthreads();
        #pragma unroll
        for (int k = 0; k < 16; ++k) {
            int i = k * 256 + t;
            int e = (tile << 12) + i;
            unsigned dmark = 0xFFFFFFFFu, s = 0;
            if (e < n_edges) {
                s     = (unsigned)load_idx_clamped(ei, e, is64, n_nodes);
                int d = load_idx_clamped(ei, (long long)n_edges + e, is64, n_nodes);
                dmark = (unsigned)d;
                atomicAdd(&cnt[d >> 8], 1);
            }
            sv[i] = s; dv[i] = dmark;
        }
        __syncthreads();
        if (cnt[t])       cur[t]       = atomicAdd(&gcur[t], cnt[t]);
        if (cnt[t + 256]) cur[t + 256] = atomicAdd(&gcur[t + 256], cnt[t + 256]);
        __syncthreads();
        #pragma unroll
        for (int k = 0; k < 16; ++k) {
            int i = k * 256 + t;
            unsigned d = dv[i];
            if (d != 0xFFFFFFFFu) {
                int pos = atomicAdd(&cur[d >> 8], 1);
                pos = pos < 0 ? 0 : (pos >= n_edges ? n_edges - 1 : pos);
                B[pos] = ((d & 255u) << 17) | sv[i];
            }
        }
        __syncthreads();
    }
}

// per-256-node-bucket: LDS hist -> 256-scan -> degc/offs/dinv -> csr place.
__global__ __launch_bounds__(256)
void csr_build2_kernel(const unsigned* __restrict__ B, const int* __restrict__ gbase,
                       int* __restrict__ degc, int* __restrict__ offs,
                       float* __restrict__ dinv, int* __restrict__ csr,
                       int n_edges, int n_nodes) {
    __shared__ int cnt[256];
    __shared__ int scn[256];
    __shared__ int cur[256];
    const int b = blockIdx.x, t = threadIdx.x;
    cnt[t] = 0;
    __syncthreads();
    const int lo = gbase[b], hi = gbase[b + 1];
    for (int i = lo + t; i < hi; i += 256) {
        unsigned v = B[i];
        atomicAdd(&cnt[v >> 17], 1);
    }
    __syncthreads();
    int v = cnt[t];
    scn[t] = v;
    __syncthreads();
    for (int off = 1; off < 256; off <<= 1) {
        int u = (t >= off) ? scn[t - off] : 0;
        __syncthreads();
        scn[t] += u;
        __syncthreads();
    }
    int e0 = lo + scn[t] - v;
    cur[t] = e0;
    int n0 = b * 256 + t;
    if (n0 < n_nodes) {
        degc[n0] = v; offs[n0] = e0;
        dinv[n0] = 1.0f / fmaxf((float)v, 1.0f);
    }
    __syncthreads();
    for (int i = lo + t; i < hi; i += 256) {
        unsigned w = B[i];
        int pos = atomicAdd(&cur[w >> 17], 1);
        pos = pos < 0 ? 0 : (pos >= n_edges ? n_edges - 1 : pos);
        csr[pos] = (int)(w & 0x1FFFFu);
    }
}

// ---------------------------------------------------------------------------
// R4-proven FUSED gather+GEMM per layer (UNCHANGED). Per tile of 16 nodes:
// 16 lane-groups run the R3 gather loop (1 node/group, lane u owns feats
// 4u..4u+3), stage the 16x64 agg tile in LDS (rows padded to 72), sync, then
// the 4 waves each MFMA one 16-column tile (proven fragment mapping).
// ---------------------------------------------------------------------------
__global__ __launch_bounds__(256)
void fused_l1_kernel(const __bf16* __restrict__ xb,
                     const int* __restrict__ offs, const int* __restrict__ degc,
                     const float* __restrict__ dinv, const int* __restrict__ csr,
                     const __bf16* __restrict__ Bl, const __bf16* __restrict__ Br,
                     const float* __restrict__ bias,
                     __bf16* __restrict__ hout, int n_nodes) {
    const int t = threadIdx.x, lane = t & 63, wave = t >> 6;
    const int quad = lane >> 4, r16 = lane & 15;
    const int grp = t >> 4, u = t & 15;          // gather role: 16 groups/block
    bf16x8 bl[2], br[2];
    #pragma unroll
    for (int ks = 0; ks < 2; ++ks) {
        int f = wave * 16 + r16, k = ks * 32 + quad * 8;
        bl[ks] = *(const bf16x8*)(Bl + f * 64 + k);
        br[ks] = *(const bf16x8*)(Br + f * 64 + k);
    }
    const float bv = bias[wave * 16 + r16];
    __shared__ __bf16 sAgg[16][72];              // padded: 144B row stride
    const int ntiles = (n_nodes + 15) >> 4;
    for (int tile = blockIdx.x; tile < ntiles; tile += gridDim.x) {
        const int n = tile * 16 + grp;
        const bool act = n < n_nodes;
        float a0 = 0.f, a1 = 0.f, a2 = 0.f, a3 = 0.f, di = 1.f;
        if (act) {
            int rs = offs[n], cnt = degc[n];
            di = dinv[n];
            int idx = (u < cnt) ? (int)__builtin_nontemporal_load(&csr[rs + u]) : 0;
            int c = 0;
            while (true) {
                idx = idx < 0 ? 0 : (idx >= n_nodes ? n_nodes - 1 : idx);
                int sj[16];
                #pragma unroll
                for (int j = 0; j < 16; ++j) sj[j] = __shfl(idx, j, 16);
                bf16x4 v[16];
                #pragma unroll
                for (int j = 0; j < 16; ++j)
                    v[j] = ((const bf16x4*)xb)[(size_t)sj[j] * 16 + u];
                #pragma unroll
                for (int j = 0; j < 16; ++j) {
                    float m = (c + j < cnt) ? 1.f : 0.f;
                    a0 = fmaf(m, (float)v[j].x, a0);
                    a1 = fmaf(m, (float)v[j].y, a1);
                    a2 = fmaf(m, (float)v[j].z, a2);
                    a3 = fmaf(m, (float)v[j].w, a3);
                }
                c += 16;
                if (c >= cnt) break;
                idx = (u < cnt - c) ? (int)__builtin_nontemporal_load(&csr[rs + c + u]) : 0;
            }
        }
        bf16x4 o;
        o.x = (__bf16)(a0 * di); o.y = (__bf16)(a1 * di);
        o.z = (__bf16)(a2 * di); o.w = (__bf16)(a3 * di);
        *(bf16x4*)(&sAgg[grp][u * 4]) = o;       // same rounding as old agg path
        __syncthreads();
        // ---- MFMA phase (ct = wave) ----
        const int m0 = tile * 16;
        int mrow = m0 + r16; if (mrow >= n_nodes) mrow = n_nodes - 1;
        bf16x8 ag[2], ax[2];
        #pragma unroll
        for (int ks = 0; ks < 2; ++ks) {
            ag[ks] = *(const bf16x8*)(&sAgg[r16][ks * 32 + quad * 8]);
            ax[ks] = *(const bf16x8*)(xb + (size_t)mrow * 64 + ks * 32 + quad * 8);
        }
        f32x4 acc = {0.f, 0.f, 0.f, 0.f};
        acc = __builtin_amdgcn_mfma_f32_16x16x32_bf16(ag[0], bl[0], acc, 0, 0, 0);
        acc = __builtin_amdgcn_mfma_f32_16x16x32_bf16(ag[1], bl[1], acc, 0, 0, 0);
        acc = __builtin_amdgcn_mfma_f32_16x16x32_bf16(ax[0], br[0], acc, 0, 0, 0);
        acc = __builtin_amdgcn_mfma_f32_16x16x32_bf16(ax[1], br[1], acc, 0, 0, 0);
        const int col = wave * 16 + r16;
        #pragma unroll
        for (int rg = 0; rg < 4; ++rg) {
            int row = m0 + quad * 4 + rg;
            if (row < n_nodes) {
                float ov = acc[rg] + bv;
                hout[(size_t)row * 64 + col] = (__bf16)fmaxf(ov, 0.f);
            }
        }
        __syncthreads();                          // protect sAgg before next tile
    }
}

__global__ __launch_bounds__(256)
void fused_l2_kernel(const __bf16* __restrict__ hb,
                     const int* __restrict__ offs, const int* __restrict__ degc,
                     const float* __restrict__ dinv, const int* __restrict__ csr,
                     const __bf16* __restrict__ Bl, const __bf16* __restrict__ Br,
                     const float* __restrict__ bias,
                     float* __restrict__ out, int n_nodes) {
    const int t = threadIdx.x, lane = t & 63, wave = t >> 6;
    const int quad = lane >> 4, r16 = lane & 15;
    const int grp = t >> 4, u = t & 15;
    bf16x8 bl[2], br[2];
    #pragma unroll
    for (int ks = 0; ks < 2; ++ks) {
        int f = wave * 16 + r16, k = ks * 32 + quad * 8;
        bl[ks] = *(const bf16x8*)(Bl + f * 64 + k);
        br[ks] = *(const bf16x8*)(Br + f * 64 + k);
    }
    const float bv = bias[wave * 16 + r16];
    __shared__ __bf16 sAgg[16][72];
    const int ntiles = (n_nodes + 15) >> 4;
    for (int tile = blockIdx.x; tile < ntiles; tile += gridDim.x) {
        const int n = tile * 16 + grp;
        const bool act = n < n_nodes;
        float a0 = 0.f, a1 = 0.f, a2 = 0.f, a3 = 0.f, di = 1.f;
        if (act) {
            int rs = offs[n], cnt = degc[n];
            di = dinv[n];
            int idx = (u < cnt) ? (int)__builtin_nontemporal_load(&csr[rs + u]) : 0;
            int c = 0;
            while (true) {
                idx = idx < 0 ? 0 : (idx >= n_nodes ? n_nodes - 1 : idx);
                int sj[16];
                #pragma unroll
                for (int j = 0; j < 16; ++j) sj[j] = __shfl(idx, j, 16);
                bf16x4 v[16];
                #pragma unroll
                for (int j = 0; j < 16; ++j)
                    v[j] = ((const bf16x4*)hb)[(size_t)sj[j] * 16 + u];
                #pragma unroll
                for (int j = 0; j < 16; ++j) {
                    float m = (c + j < cnt) ? 1.f : 0.f;
                    a0 = fmaf(m, (float)v[j].x, a0);
                    a1 = fmaf(m, (float)v[j].y, a1);
                    a2 = fmaf(m, (float)v[j].z, a2);
                    a3 = fmaf(m, (float)v[j].w, a3);
                }
                c += 16;
                if (c >= cnt) break;
                idx = (u < cnt - c) ? (int)__builtin_nontemporal_load(&csr[rs + c + u]) : 0;
            }
        }
        bf16x4 o;
        o.x = (__bf16)(a0 * di); o.y = (__bf16)(a1 * di);
        o.z = (__bf16)(a2 * di); o.w = (__bf16)(a3 * di);
        *(bf16x4*)(&sAgg[grp][u * 4]) = o;
        __syncthreads();
        const int m0 = tile * 16;
        int mrow = m0 + r16; if (mrow >= n_nodes) mrow = n_nodes - 1;
        bf16x8 ag[2], ah[2];
        #pragma unroll
        for (int ks = 0; ks < 2; ++ks) {
            ag[ks] = *(const bf16x8*)(&sAgg[r16][ks * 32 + quad * 8]);
            ah[ks] = *(const bf16x8*)(hb + (size_t)mrow * 64 + ks * 32 + quad * 8);
        }
        f32x4 acc = {0.f, 0.f, 0.f, 0.f};
        acc = __builtin_amdgcn_mfma_f32_16x16x32_bf16(ag[0], bl[0], acc, 0, 0, 0);
        acc = __builtin_amdgcn_mfma_f32_16x16x32_bf16(ag[1], bl[1], acc, 0, 0, 0);
        acc = __builtin_amdgcn_mfma_f32_16x16x32_bf16(ah[0], br[0], acc, 0, 0, 0);
        acc = __builtin_amdgcn_mfma_f32_16x16x32_bf16(ah[1], br[1], acc, 0, 0, 0);
        const int col = wave * 16 + r16;
        #pragma unroll
        for (int rg = 0; rg < 4; ++rg) {
            int row = m0 + quad * 4 + rg;
            if (row < n_nodes) out[(size_t)row * 64 + col] = acc[rg] + bv;
        }
        __syncthreads();
    }
}

// ---------------------------------------------------------------------------
// Scans (T3/T4 paths)
// ---------------------------------------------------------------------------
__global__ __launch_bounds__(256)
void scan_partial_kernel(const int* __restrict__ degc, int* __restrict__ part, int n_nodes) {
    __shared__ int sh[256];
    int i = blockIdx.x * 256 + threadIdx.x;
    sh[threadIdx.x] = (i < n_nodes) ? degc[i] : 0;
    __syncthreads();
    for (int off = 128; off > 0; off >>= 1) {
        if (threadIdx.x < off) sh[threadIdx.x] += sh[threadIdx.x + off];
        __syncthreads();
    }
    if (threadIdx.x == 0) part[blockIdx.x] = sh[0];
}

__global__ void scan_top_kernel(int* __restrict__ part, int nparts) {
    __shared__ int sh[512];
    int t = threadIdx.x;
    int v = (t < nparts) ? part[t] : 0;
    sh[t] = v;
    __syncthreads();
    for (int off = 1; off < 512; off <<= 1) {
        int u = (t >= off) ? sh[t - off] : 0;
        __syncthreads();
        sh[t] += u;
        __syncthreads();
    }
    if (t < nparts) part[t] = sh[t] - v;   // exclusive
}

__global__ __launch_bounds__(256)
void scan_final_kernel(const int* __restrict__ degc, const int* __restrict__ part,
                       int* __restrict__ offs, float* __restrict__ deg_inv, int n_nodes) {
    __shared__ int sh[256];
    int t = threadIdx.x;
    int i = blockIdx.x * 256 + t;
    int v = (i < n_nodes) ? degc[i] : 0;
    sh[t] = v;
    __syncthreads();
    for (int off = 1; off < 256; off <<= 1) {
        int u = (t >= off) ? sh[t - off] : 0;
        __syncthreads();
        sh[t] += u;
        __syncthreads();
    }
    if (i < n_nodes) {
        offs[i]    = sh[t] - v + part[blockIdx.x];
        deg_inv[i] = 1.0f / fmaxf((float)v, 1.0f);
    }
}

// ---------------------------------------------------------------------------
// T3 path: global-atomic hist + cursor scatter.
// ---------------------------------------------------------------------------
__global__ __launch_bounds__(256)
void hist_kernel(const void* __restrict__ ei, const int* __restrict__ flagp,
                 int* __restrict__ degc, int n_edges, int n_nodes) {
    int e = blockIdx.x * 256 + threadIdx.x;
    if (e >= n_edges) return;
    int d = load_idx_clamped(ei, (long long)n_edges + e, *flagp, n_nodes);
    atomicAdd(&degc[d], 1);
}

__global__ __launch_bounds__(256)
void csr_scatter_kernel(const void* __restrict__ ei, const int* __restrict__ flagp,
                        const int* __restrict__ offs, int* __restrict__ cursor,
                        int* __restrict__ csr, int n_edges, int n_nodes) {
    int e = blockIdx.x * 256 + threadIdx.x;
    if (e >= n_edges) return;
    int is64 = *flagp;
    int s = load_idx_clamped(ei, e, is64, n_nodes);
    int d = load_idx_clamped(ei, (long long)n_edges + e, is64, n_nodes);
    int pos = offs[d] + atomicAdd(&cursor[d], 1);
    pos = pos < 0 ? 0 : (pos >= n_edges ? n_edges - 1 : pos);
    csr[pos] = s;
}

// ---------------------------------------------------------------------------
// Casts (T3 fallback path)
// ---------------------------------------------------------------------------
__global__ __launch_bounds__(256)
void cast_w_kernel(const float* __restrict__ a, const float* __restrict__ b,
                   const float* __restrict__ c, const float* __restrict__ d,
                   __bf16* __restrict__ o) {
    int i = blockIdx.x * 256 + threadIdx.x;
    if (i < FEAT * FEAT) {
        o[i]         = (__bf16)a[i];
        o[4096 + i]  = (__bf16)b[i];
        o[8192 + i]  = (__bf16)c[i];
        o[12288 + i] = (__bf16)d[i];
    }
}

// ---------------------------------------------------------------------------
// Standalone gather kernels (T3 fallback path; unchanged, proven).
// ---------------------------------------------------------------------------
__global__ __launch_bounds__(256)
void gather_bf16_kernel(const __bf16* __restrict__ hin, const int* __restrict__ offs,
                        const int* __restrict__ degc, const float* __restrict__ dinv,
                        const int* __restrict__ csr, __bf16* __restrict__ agg,
                        int n_nodes) {
    const int t = threadIdx.x, u = t & 15;
    const int g0 = blockIdx.x * 16 + (t >> 4);
    const int ng = gridDim.x * 16;
    if (g0 >= n_nodes) return;
    int rs = offs[g0], cnt = degc[g0];
    float di = dinv[g0];
    int idx = (u < cnt) ? (int)__builtin_nontemporal_load(&csr[rs + u]) : 0;
    for (int n = g0; n < n_nodes; n += ng) {
        const int nn = n + ng;
        int rs2 = 0, cnt2 = 0;
        float di2 = 1.0f;
        if (nn < n_nodes) { rs2 = offs[nn]; cnt2 = degc[nn]; di2 = dinv[nn]; }
        float a0 = 0.f, a1 = 0.f, a2 = 0.f, a3 = 0.f;
        int c = 0;
        while (true) {
            idx = idx < 0 ? 0 : (idx >= n_nodes ? n_nodes - 1 : idx);
            int sj[16];
            #pragma unroll
            for (int j = 0; j < 16; ++j) sj[j] = __shfl(idx, j, 16);
            bf16x4 v[16];
            #pragma unroll
            for (int j = 0; j < 16; ++j)
                v[j] = ((const bf16x4*)hin)[(size_t)sj[j] * 16 + u];
            #pragma unroll
            for (int j = 0; j < 16; ++j) {
                float m = (c + j < cnt) ? 1.f : 0.f;
                a0 = fmaf(m, (float)v[j].x, a0);
                a1 = fmaf(m, (float)v[j].y, a1);
                a2 = fmaf(m, (float)v[j].z, a2);
                a3 = fmaf(m, (float)v[j].w, a3);
            }
            c += 16;
            if (c >= cnt) break;
            idx = (u < cnt - c) ? (int)__builtin_nontemporal_load(&csr[rs + c + u]) : 0;
        }
        idx = (nn < n_nodes && u < cnt2)
                  ? (int)__builtin_nontemporal_load(&csr[rs2 + u]) : 0;
        bf16x4 o;
        o.x = (__bf16)(a0 * di); o.y = (__bf16)(a1 * di);
        o.z = (__bf16)(a2 * di); o.w = (__bf16)(a3 * di);
        ((bf16x4*)agg)[(size_t)n * 16 + u] = o;
        rs = rs2; cnt = cnt2; di = di2;
    }
}

__global__ __launch_bounds__(256)
void gather_f32_kernel(const float* __restrict__ xin, const int* __restrict__ offs,
                       const int* __restrict__ degc, const float* __restrict__ dinv,
                       const int* __restrict__ csr, __bf16* __restrict__ agg,
                       int n_nodes) {
    const int t = threadIdx.x, lane = t & 63, g = lane >> 4, u = lane & 15;
    const int gw = blockIdx.x * 4 + (t >> 6), nw = gridDim.x * 4;
    for (int n = gw; n < n_nodes; n += nw) {
        int rs = offs[n], cnt = degc[n];
        float a0 = 0.f, a1 = 0.f, a2 = 0.f, a3 = 0.f;
        for (int c = 0; c < cnt; c += 64) {
            int chunk = min(64, cnt - c);
            int myid = (lane < chunk) ? (int)__builtin_nontemporal_load(&csr[rs + c + lane]) : 0;
            myid = myid < 0 ? 0 : (myid >= n_nodes ? n_nodes - 1 : myid);
            for (int q = 0; q < chunk; q += 16) {
                int q0 = q + g, q1 = q + g + 4, q2 = q + g + 8, q3 = q + g + 12;
                int s0 = __shfl(myid, q0), s1 = __shfl(myid, q1);
                int s2 = __shfl(myid, q2), s3 = __shfl(myid, q3);
                float m0 = (q0 < chunk) ? 1.f : 0.f;
                float m1 = (q1 < chunk) ? 1.f : 0.f;
                float m2 = (q2 < chunk) ? 1.f : 0.f;
                float m3 = (q3 < chunk) ? 1.f : 0.f;
                float4 v0 = ((const float4*)xin)[(size_t)s0 * 16 + u];
                float4 v1 = ((const float4*)xin)[(size_t)s1 * 16 + u];
                float4 v2 = ((const float4*)xin)[(size_t)s2 * 16 + u];
                float4 v3 = ((const float4*)xin)[(size_t)s3 * 16 + u];
                a0 = fmaf(m0, v0.x, a0); a1 = fmaf(m0, v0.y, a1);
                a2 = fmaf(m0, v0.z, a2); a3 = fmaf(m0, v0.w, a3);
                a0 = fmaf(m1, v1.x, a0); a1 = fmaf(m1, v1.y, a1);
                a2 = fmaf(m1, v1.z, a2); a3 = fmaf(m1, v1.w, a3);
                a0 = fmaf(m2, v2.x, a0); a1 = fmaf(m2, v2.y, a1);
                a2 = fmaf(m2, v2.z, a2); a3 = fmaf(m2, v2.w, a3);
                a0 = fmaf(m3, v3.x, a0); a1 = fmaf(m3, v3.y, a1);
                a2 = fmaf(m3, v3.z, a2); a3 = fmaf(m3, v3.w, a3);
            }
        }
        a0 += __shfl_xor(a0, 16); a1 += __shfl_xor(a1, 16);
        a2 += __shfl_xor(a2, 16); a3 += __shfl_xor(a3, 16);
        a0 += __shfl_xor(a0, 32); a1 += __shfl_xor(a1, 32);
        a2 += __shfl_xor(a2, 32); a3 += __shfl_xor(a3, 32);
        if (g == 0) {
            float di = dinv[n];
            bf16x4 o;
            o.x = (__bf16)(a0 * di); o.y = (__bf16)(a1 * di);
            o.z = (__bf16)(a2 * di); o.w = (__bf16)(a3 * di);
            ((bf16x4*)agg)[(size_t)n * 16 + u] = o;
        }
    }
}

// ---------------------------------------------------------------------------
// Standalone MFMA GEMMs (T3 fallback path; unchanged, proven).
// ---------------------------------------------------------------------------
__global__ __launch_bounds__(256)
void gemm_l1_kernel(const __bf16* __restrict__ Ag, const float* __restrict__ xin,
                    const __bf16* __restrict__ Bl, const __bf16* __restrict__ Br,
                    const float* __restrict__ bias,
                    __bf16* __restrict__ hout, int n_nodes) {
    const int t = threadIdx.x, lane = t & 63;
    const int quad = lane >> 4, r16 = lane & 15;
    bf16x8 bl[2][4], br[2][4];
    #pragma unroll
    for (int ks = 0; ks < 2; ++ks)
        #pragma unroll
        for (int ct = 0; ct < 4; ++ct) {
            int f = ct * 16 + r16, k = ks * 32 + quad * 8;
            bl[ks][ct] = *(const bf16x8*)(Bl + f * 64 + k);
            br[ks][ct] = *(const bf16x8*)(Br + f * 64 + k);
        }
    const int m0 = (blockIdx.x * 4 + (t >> 6)) * 16;
    if (m0 >= n_nodes) return;
    int mrow = m0 + r16; if (mrow >= n_nodes) mrow = n_nodes - 1;
    bf16x8 ag[2], ax[2];
    #pragma unroll
    for (int ks = 0; ks < 2; ++ks) {
        ag[ks] = *(const bf16x8*)(Ag + (size_t)mrow * 64 + ks * 32 + quad * 8);
        const float* xr = xin + (size_t)mrow * 64 + ks * 32 + quad * 8;
        float4 p = *(const float4*)xr;
        float4 q = *(const float4*)(xr + 4);
        union { bf16x8 v; __bf16 e[8]; } U;
        U.e[0] = (__bf16)p.x; U.e[1] = (__bf16)p.y; U.e[2] = (__bf16)p.z; U.e[3] = (__bf16)p.w;
        U.e[4] = (__bf16)q.x; U.e[5] = (__bf16)q.y; U.e[6] = (__bf16)q.z; U.e[7] = (__bf16)q.w;
        ax[ks] = U.v;
    }
    #pragma unroll
    for (int ct = 0; ct < 4; ++ct) {
        f32x4 acc = {0.f, 0.f, 0.f, 0.f};
        acc = __builtin_amdgcn_mfma_f32_16x16x32_bf16(ag[0], bl[0][ct], acc, 0, 0, 0);
        acc = __builtin_amdgcn_mfma_f32_16x16x32_bf16(ag[1], bl[1][ct], acc, 0, 0, 0);
        acc = __builtin_amdgcn_mfma_f32_16x16x32_bf16(ax[0], br[0][ct], acc, 0, 0, 0);
        acc = __builtin_amdgcn_mfma_f32_16x16x32_bf16(ax[1], br[1][ct], acc, 0, 0, 0);
        int col = ct * 16 + r16;
        float bv = bias[col];
        #pragma unroll
        for (int rg = 0; rg < 4; ++rg) {
            int n = m0 + quad * 4 + rg;
            if (n < n_nodes) {
                float o = acc[rg] + bv;
                hout[(size_t)n * 64 + col] = (__bf16)fmaxf(o, 0.f);
            }
        }
    }
}

__global__ __launch_bounds__(256)
void gemm_l2_kernel(const __bf16* __restrict__ Ag, const __bf16* __restrict__ Ah,
                    const __bf16* __restrict__ Bl, const __bf16* __restrict__ Br,
                    const float* __restrict__ bias,
                    float* __restrict__ out, int n_nodes) {
    const int t = threadIdx.x, lane = t & 63;
    const int quad = lane >> 4, r16 = lane & 15;
    bf16x8 bl[2][4], br[2][4];
    #pragma unroll
    for (int ks = 0; ks < 2; ++ks)
        #pragma unroll
        for (int ct = 0; ct < 4; ++ct) {
            int f = ct * 16 + r16, k = ks * 32 + quad * 8;
            bl[ks][ct] = *(const bf16x8*)(Bl + f * 64 + k);
            br[ks][ct] = *(const bf16x8*)(Br + f * 64 + k);
        }
    const int m0 = (blockIdx.x * 4 + (t >> 6)) * 16;
    if (m0 >= n_nodes) return;
    int mrow = m0 + r16; if (mrow >= n_nodes) mrow = n_nodes - 1;
    bf16x8 ag[2], ah[2];
    #pragma unroll
    for (int ks = 0; ks < 2; ++ks) {
        ag[ks] = *(const bf16x8*)(Ag + (size_t)mrow * 64 + ks * 32 + quad * 8);
        ah[ks] = *(const bf16x8*)(Ah + (size_t)mrow * 64 + ks * 32 + quad * 8);
    }
    #pragma unroll
    for (int ct = 0; ct < 4; ++ct) {
        f32x4 acc = {0.f, 0.f, 0.f, 0.f};
        acc = __builtin_amdgcn_mfma_f32_16x16x32_bf16(ag[0], bl[0][ct], acc, 0, 0, 0);
        acc = __builtin_amdgcn_mfma_f32_16x16x32_bf16(ag[1], bl[1][ct], acc, 0, 0, 0);
        acc = __builtin_amdgcn_mfma_f32_16x16x32_bf16(ah[0], br[0][ct], acc, 0, 0, 0);
        acc = __builtin_amdgcn_mfma_f32_16x16x32_bf16(ah[1], br[1][ct], acc, 0, 0, 0);
        int col = ct * 16 + r16;
        float bv = bias[col];
        #pragma unroll
        for (int rg = 0; rg < 4; ++rg) {
            int n = m0 + quad * 4 + rg;
            if (n < n_nodes) out[(size_t)n * 64 + col] = acc[rg] + bv;
        }
    }
}

// ---------------------------------------------------------------------------
// T4 fallback: fused LDS kernels (unchanged).
// ---------------------------------------------------------------------------
__global__ __launch_bounds__(256)
void sage_fused_l1_kernel(const float* __restrict__ xin,
                          const int* __restrict__ offs, const int* __restrict__ degc,
                          const float* __restrict__ deg_inv, const int* __restrict__ csr,
                          const float* __restrict__ Wl, const float* __restrict__ bias,
                          const float* __restrict__ Wr,
                          __bf16* __restrict__ hout, int n_nodes) {
    __shared__ float WlT[FEAT * 65], WrT[FEAT * 65], bsh[FEAT];
    __shared__ float aggS[4][FEAT], selfS[4][FEAT];
    const int t = threadIdx.x;
    #pragma unroll
    for (int p = 0; p < 16; ++p) {
        int i = t + p * 256, j = i >> 6, k = i & 63;
        WlT[k * 65 + j] = Wl[i];
        WrT[k * 65 + j] = Wr[i];
    }
    if (t < FEAT) bsh[t] = bias[t];
    __syncthreads();
    const int w = t >> 6, f = t & 63;
    const int n_groups = (n_nodes + 3) >> 2;
    for (int g = blockIdx.x; g < n_groups; g += gridDim.x) {
        int n = g * 4 + w;
        bool act = (n < n_nodes);
        if (act) {
            int rs = offs[n], cnt = degc[n];
            float acc = 0.f;
            for (int c = 0; c < cnt; c += 64) {
                int chunk = min(64, cnt - c);
                int myid = (f < chunk) ? csr[rs + c + f] : 0;
                #pragma unroll 4
                for (int q = 0; q < chunk; ++q) {
                    int s = __shfl(myid, q);
                    acc += xin[(long long)s * FEAT + f];
                }
            }
            aggS[w][f]  = acc * deg_inv[n];
            selfS[w][f] = xin[(long long)n * FEAT + f];
        }
        __syncthreads();
        if (act) {
            float o = bsh[f];
            #pragma unroll
            for (int k = 0; k < FEAT; ++k) {
                o = fmaf(aggS[w][k],  WlT[k * 65 + f], o);
                o = fmaf(selfS[w][k], WrT[k * 65 + f], o);
            }
            o = fmaxf(o, 0.f);
            hout[(long long)n * FEAT + f] = (__bf16)o;
        }
        __syncthreads();
    }
}

__global__ __launch_bounds__(256)
void sage_fused_l2_kernel(const __bf16* __restrict__ hin,
                          const int* __restrict__ offs, const int* __restrict__ degc,
                          const float* __restrict__ deg_inv, const int* __restrict__ csr,
                          const float* __restrict__ Wl, const float* __restrict__ bias,
                          const float* __restrict__ Wr,
                          float* __restrict__ out, int n_nodes) {
    __shared__ float WlT[FEAT * 65], WrT[FEAT * 65], bsh[FEAT];
    __shared__ float aggS[4][FEAT], selfS[4][FEAT];
    const int t = threadIdx.x;
    #pragma unroll
    for (int p = 0; p < 16; ++p) {
        int i = t + p * 256, j = i >> 6, k = i & 63;
        WlT[k * 65 + j] = Wl[i];
        WrT[k * 65 + j] = Wr[i];
    }
    if (t < FEAT) bsh[t] = bias[t];
    __syncthreads();
    const int w = t >> 6, f = t & 63;
    const int n_groups = (n_nodes + 3) >> 2;
    for (int g = blockIdx.x; g < n_groups; g += gridDim.x) {
        int n = g * 4 + w;
        bool act = (n < n_nodes);
        if (act) {
            int rs = offs[n], cnt = degc[n];
            float acc = 0.f;
            for (int c = 0; c < cnt; c += 64) {
                int chunk = min(64, cnt - c);
                int myid = (f < chunk) ? csr[rs + c + f] : 0;
                #pragma unroll 4
                for (int q = 0; q < chunk; ++q) {
                    int s = __shfl(myid, q);
                    acc += (float)hin[(long long)s * FEAT + f];
                }
            }
            aggS[w][f]  = acc * deg_inv[n];
            selfS[w][f] = (float)hin[(long long)n * FEAT + f];
        }
        __syncthreads();
        if (act) {
            float o = bsh[f];
            #pragma unroll
            for (int k = 0; k < FEAT; ++k) {
                o = fmaf(aggS[w][k],  WlT[k * 65 + f], o);
                o = fmaf(selfS[w][k], WrT[k * 65 + f], o);
            }
            out[(long long)n * FEAT + f] = o;
        }
        __syncthreads();
    }
}

// ---------------------------------------------------------------------------
// Launch
// ---------------------------------------------------------------------------
extern "C" void kernel_launch(void* const* d_in, const int* in_sizes, int n_in,
                              void* d_out, int out_size, void* d_ws, size_t ws_size,
                              hipStream_t stream) {
    const float* x   = (const float*)d_in[0];
    const void*  ei  = d_in[1];
    const float* W1l = (const float*)d_in[2];
    const float* b1  = (const float*)d_in[3];
    const float* W1r = (const float*)d_in[4];
    const float* W2l = (const float*)d_in[5];
    const float* b2  = (const float*)d_in[6];
    const float* W2r = (const float*)d_in[7];
    float* out = (float*)d_out;

    const int n_nodes = in_sizes[0] / FEAT;
    const int n_edges = in_sizes[1] / 2;
    const int nparts  = (n_nodes + 255) / 256;     // <= 512
    const int egrid   = (n_edges + 255) / 256;
    const int NB256   = (n_nodes + 255) >> 8;      // 256-node buckets, <= 512

    char* ws = (char*)d_ws;
    auto al = [](size_t v) { return (v + 255) & ~(size_t)255; };

    // ---- T1 layout ----
    size_t o = 0;
    int*      flag  = (int*)(ws + o);      o += 256;
    int*      degc  = (int*)(ws + o);      o += al((size_t)n_nodes * 4);
    float*    dinv  = (float*)(ws + o);    o += al((size_t)n_nodes * 4);
    int*      offs  = (int*)(ws + o);      o += al((size_t)n_nodes * 4);
    int*      gcnt  = (int*)(ws + o);      o += al(516 * 4);   // 512 + ticket
    int*      gbase = (int*)(ws + o);      o += al(513 * 4);
    int*      gcur  = (int*)(ws + o);      o += al(512 * 4);
    unsigned* B     = (unsigned*)(ws + o); o += al((size_t)n_edges * 4);
    int*      csr   = (int*)(ws + o);      o += al((size_t)n_edges * 4);
    __bf16*   xb    = (__bf16*)(ws + o);   o += al((size_t)n_nodes * FEAT * 2);
    __bf16*   wb    = (__bf16*)(ws + o);   o += al((size_t)4 * FEAT * FEAT * 2);
    __bf16*   h     = (__bf16*)(ws + o);   o += al((size_t)n_nodes * FEAT * 2);
    const size_t needT1 = o;

    // ---- T3 layout (proven fallback) ----
    size_t o3 = 0;
    int*    flag3   = (int*)(ws + o3);    o3 += 256;
    int*    degc3   = (int*)(ws + o3);    o3 += al((size_t)n_nodes * 4);
    float*  dinv3   = (float*)(ws + o3);  o3 += al((size_t)n_nodes * 4);
    int*    offs3   = (int*)(ws + o3);    o3 += al((size_t)n_nodes * 4);
    int*    cursor3 = (int*)(ws + o3);    o3 += al((size_t)n_nodes * 4);
    int*    part3   = (int*)(ws + o3);    o3 += al(2048);
    int*    csr3    = (int*)(ws + o3);    o3 += al((size_t)n_edges * 4);
    const size_t commonEnd3 = o3;
    __bf16* wb3  = (__bf16*)(ws + o3);    o3 += al((size_t)4 * FEAT * FEAT * 2);
    __bf16* agg3 = (__bf16*)(ws + o3);    o3 += al((size_t)n_nodes * FEAT * 2);
    __bf16* h3   = (__bf16*)(ws + o3);    o3 += al((size_t)n_nodes * FEAT * 2);
    const size_t needT3 = o3;

    const int n4 = n_nodes * FEAT / 4;
    const int mgrid = (n_nodes + 63) / 64;
    const int ggrid = 2048;
    const int ntiles = (n_edges + 4095) >> 12;
    const int ftiles = (n_nodes + 15) >> 4;
    const int fgrid2 = ftiles < 2048 ? ftiles : 2048;

    if (ws_size >= needT1 && n_nodes <= 131072) {
        detect_castw_kernel<<<17, 256, 0, stream>>>((const unsigned*)ei, flag, gcnt,
                                                    W1l, W1r, W2l, W2r, wb);
        bucket_count_castx_kernel<<<1536, 256, 0, stream>>>(ei, flag, gcnt, gbase, gcur,
                                                            x, xb, n4, n_edges, n_nodes);
        multisplit_kernel<<<ntiles, 256, 0, stream>>>(ei, flag, gcur, B, n_edges, n_nodes);
        csr_build2_kernel<<<NB256, 256, 0, stream>>>(B, gbase, degc, offs, dinv, csr, n_edges, n_nodes);
        fused_l1_kernel<<<fgrid2, 256, 0, stream>>>(xb, offs, degc, dinv, csr,
                                                    wb, wb + 4096, b1, h, n_nodes);
        fused_l2_kernel<<<fgrid2, 256, 0, stream>>>(h, offs, degc, dinv, csr,
                                                    wb + 8192, wb + 12288, b2, out, n_nodes);
    } else if (ws_size >= needT3) {
        zero2_kernel<<<nparts, 256, 0, stream>>>(degc3, cursor3, n_nodes);
        detect_idx_kernel<<<1, 256, 0, stream>>>((const unsigned*)ei, flag3, part3);
        hist_kernel<<<egrid, 256, 0, stream>>>(ei, flag3, degc3, n_edges, n_nodes);
        scan_partial_kernel<<<nparts, 256, 0, stream>>>(degc3, part3, n_nodes);
        scan_top_kernel<<<1, 512, 0, stream>>>(part3, nparts);
        scan_final_kernel<<<nparts, 256, 0, stream>>>(degc3, part3, offs3, dinv3, n_nodes);
        csr_scatter_kernel<<<egrid, 256, 0, stream>>>(ei, flag3, offs3, cursor3, csr3, n_edges, n_nodes);
        cast_w_kernel<<<16, 256, 0, stream>>>(W1l, W1r, W2l, W2r, wb3);
        gather_f32_kernel<<<ggrid, 256, 0, stream>>>(x, offs3, degc3, dinv3, csr3, agg3, n_nodes);
        gemm_l1_kernel<<<mgrid, 256, 0, stream>>>(agg3, x, wb3, wb3 + 4096, b1, h3, n_nodes);
        gather_bf16_kernel<<<ggrid, 256, 0, stream>>>(h3, offs3, degc3, dinv3, csr3, agg3, n_nodes);
        gemm_l2_kernel<<<mgrid, 256, 0, stream>>>(agg3, h3, wb3 + 8192, wb3 + 12288, b2, out, n_nodes);
    } else {
        __bf16* hf = (__bf16*)(ws + commonEnd3);
        zero2_kernel<<<nparts, 256, 0, stream>>>(degc3, cursor3, n_nodes);
        detect_idx_kernel<<<1, 256, 0, stream>>>((const unsigned*)ei, flag3, part3);
        hist_kernel<<<egrid, 256, 0, stream>>>(ei, flag3, degc3, n_edges, n_nodes);
        scan_partial_kernel<<<nparts, 256, 0, stream>>>(degc3, part3, n_nodes);
        scan_top_kernel<<<1, 512, 0, stream>>>(part3, nparts);
        scan_final_kernel<<<nparts, 256, 0, stream>>>(degc3, part3, offs3, dinv3, n_nodes);
        csr_scatter_kernel<<<egrid, 256, 0, stream>>>(ei, flag3, offs3, cursor3, csr3, n_edges, n_nodes);
        const int n_groups = (n_nodes + 3) / 4;
        const int fgrid = n_groups < 4096 ? n_groups : 4096;
        sage_fused_l1_kernel<<<fgrid, 256, 0, stream>>>(x, offs3, degc3, dinv3, csr3,
                                                        W1l, b1, W1r, hf, n_nodes);
        sage_fused_l2_kernel<<<fgrid, 256, 0, stream>>>(hf, offs3, degc3, dinv3, csr3,
                                                        W2l, b2, W2r, out, n_nodes);
    }
}

// Round 8
// 238.151 us; speedup vs baseline: 6.2526x; 1.0724x over previous
//
#include <hip/hip_runtime.h>
#include <hip/hip_bf16.h>

#define FEAT 64

typedef __bf16 bf16x8 __attribute__((ext_vector_type(8)));
typedef __bf16 bf16x4 __attribute__((ext_vector_type(4)));
typedef float  f32x4  __attribute__((ext_vector_type(4)));

// ---------------------------------------------------------------------------
// JOURNAL:
// R4 = this exact code, measured 239.98us. R6 changed the chain (last-block
// ticket scan + 256-node buckets) and regressed to 255.4us with byte-identical
// fused-kernel counters -> chain edits hurt (B-write fragmentation at small
// buckets; threadfence+ticket on all count blocks). R5's edge-centric LDS
// atomics: 685us/layer (64 serialized ds_add/edge/thread) -- never again.
// This round: exact R4 restore to disambiguate regression vs run noise.
// ---------------------------------------------------------------------------

// ---------------------------------------------------------------------------
// Zero kernel (hipMemsetAsync may execute at capture time -> poisoned replay).
// ---------------------------------------------------------------------------
__global__ __launch_bounds__(256)
void zero2_kernel(int* __restrict__ a, int* __restrict__ b, int n) {
    int i = blockIdx.x * 256 + threadIdx.x;
    if (i < n) { a[i] = 0; b[i] = 0; }
}

// ---------------------------------------------------------------------------
// detect + cast_w fused (block 0 sniffs int64-ness & zeroes gcnt;
// blocks 1..16 cast the 4 weight matrices). Saves one launch+drain.
// ---------------------------------------------------------------------------
__global__ void detect_castw_kernel(const unsigned* __restrict__ w, int* __restrict__ flag,
                                    int* __restrict__ zcnt,
                                    const float* __restrict__ a, const float* __restrict__ b,
                                    const float* __restrict__ c, const float* __restrict__ d,
                                    __bf16* __restrict__ o) {
    if (blockIdx.x == 0) {
        __shared__ int any_nz;
        if (threadIdx.x == 0) any_nz = 0;
        __syncthreads();
        if (w[2 * threadIdx.x + 1] != 0u) atomicOr(&any_nz, 1);  // first 2KB only
        zcnt[threadIdx.x] = 0;
        zcnt[threadIdx.x + 256] = 0;
        __syncthreads();
        if (threadIdx.x == 0) *flag = (any_nz == 0) ? 1 : 0;
    } else {
        int i = (blockIdx.x - 1) * 256 + threadIdx.x;
        if (i < FEAT * FEAT) {
            o[i]         = (__bf16)a[i];
            o[4096 + i]  = (__bf16)b[i];
            o[8192 + i]  = (__bf16)c[i];
            o[12288 + i] = (__bf16)d[i];
        }
    }
}

// T3-path detect (kept).
__global__ void detect_idx_kernel(const unsigned* __restrict__ w, int* __restrict__ flag,
                                  int* __restrict__ zcnt) {
    __shared__ int any_nz;
    if (threadIdx.x == 0) any_nz = 0;
    __syncthreads();
    if (w[2 * threadIdx.x + 1] != 0u) atomicOr(&any_nz, 1);
    zcnt[threadIdx.x] = 0;
    zcnt[threadIdx.x + 256] = 0;
    __syncthreads();
    if (threadIdx.x == 0) *flag = (any_nz == 0) ? 1 : 0;
}

// 4-byte index load: node ids are < 2^17, so for int64 input the high dword
// is always zero (sniffer-verified) -> read only the low dword.
__device__ __forceinline__ int load_idx_clamped(const void* ei, long long i, int is64, int n_nodes) {
    int v = is64 ? ((const int*)ei)[2 * i] : ((const int*)ei)[i];
    v = v < 0 ? 0 : v;
    return v >= n_nodes ? n_nodes - 1 : v;   // identity when data is sane
}

// ---------------------------------------------------------------------------
// T1 CSR build == two-level counting sort, bucket = dst>>9 (512 nodes/bucket).
// Pack: (d&511)<<17 | s  (requires n_nodes <= 131072; guarded at launch).
// ---------------------------------------------------------------------------

// bucket_count + cast_x fused. Blocks <512 do the LDS-hist count path
// (grid-stride fixed at 512*256); blocks >=512 cast x->bf16. Per-block
// uniform branch, so the count path's __syncthreads is legal.
__global__ __launch_bounds__(256)
void bucket_count_castx_kernel(const void* __restrict__ ei, const int* __restrict__ flagp,
                               int* __restrict__ gcnt,
                               const float* __restrict__ x, __bf16* __restrict__ xb, int n4,
                               int n_edges, int n_nodes) {
    __shared__ int cnt[512];
    const int t = threadIdx.x;
    if (blockIdx.x < 512) {
        cnt[t] = 0; cnt[t + 256] = 0;
        __syncthreads();
        const int is64 = *flagp;
        for (int e = blockIdx.x * 256 + t; e < n_edges; e += 512 * 256) {
            int d = load_idx_clamped(ei, (long long)n_edges + e, is64, n_nodes);
            atomicAdd(&cnt[d >> 9], 1);
        }
        __syncthreads();
        if (cnt[t])       atomicAdd(&gcnt[t], cnt[t]);
        if (cnt[t + 256]) atomicAdd(&gcnt[t + 256], cnt[t + 256]);
    } else {
        const int nb = gridDim.x - 512;
        for (int i = (blockIdx.x - 512) * 256 + t; i < n4; i += nb * 256) {
            float4 v = ((const float4*)x)[i];
            bf16x4 o;
            o.x = (__bf16)v.x; o.y = (__bf16)v.y; o.z = (__bf16)v.z; o.w = (__bf16)v.w;
            ((bf16x4*)xb)[i] = o;
        }
    }
}

__global__ void bucket_scan_kernel(const int* __restrict__ gcnt, int* __restrict__ gbase,
                                   int* __restrict__ gcur, int n_edges) {
    __shared__ int sh[512];
    int t = threadIdx.x;
    int v = gcnt[t];
    sh[t] = v;
    __syncthreads();
    for (int off = 1; off < 512; off <<= 1) {
        int u = (t >= off) ? sh[t - off] : 0;
        __syncthreads();
        sh[t] += u;
        __syncthreads();
    }
    int excl = sh[t] - v;
    gbase[t] = excl;
    gcur[t]  = excl;
    if (t == 511) gbase[512] = n_edges;
}

__global__ __launch_bounds__(256)
void multisplit_kernel(const void* __restrict__ ei, const int* __restrict__ flagp,
                       int* __restrict__ gcur, unsigned* __restrict__ B,
                       int n_edges, int n_nodes) {
    __shared__ unsigned sv[4096];
    __shared__ unsigned dv[4096];
    __shared__ int cnt[512];
    __shared__ int cur[512];
    const int t = threadIdx.x;
    const int is64 = *flagp;
    const int ntiles = (n_edges + 4095) >> 12;
    for (int tile = blockIdx.x; tile < ntiles; tile += gridDim.x) {
        cnt[t] = 0; cnt[t + 256] = 0;
        __syncthreads();
        #pragma unroll
        for (int k = 0; k < 16; ++k) {
            int i = k * 256 + t;
            int e = (tile << 12) + i;
            unsigned dmark = 0xFFFFFFFFu, s = 0;
            if (e < n_edges) {
                s     = (unsigned)load_idx_clamped(ei, e, is64, n_nodes);
                int d = load_idx_clamped(ei, (long long)n_edges + e, is64, n_nodes);
                dmark = (unsigned)d;
                atomicAdd(&cnt[d >> 9], 1);
            }
            sv[i] = s; dv[i] = dmark;
        }
        __syncthreads();
        if (cnt[t])       cur[t]       = atomicAdd(&gcur[t], cnt[t]);
        if (cnt[t + 256]) cur[t + 256] = atomicAdd(&gcur[t + 256], cnt[t + 256]);
        __syncthreads();
        #pragma unroll
        for (int k = 0; k < 16; ++k) {
            int i = k * 256 + t;
            unsigned d = dv[i];
            if (d != 0xFFFFFFFFu) {
                int pos = atomicAdd(&cur[d >> 9], 1);
                pos = pos < 0 ? 0 : (pos >= n_edges ? n_edges - 1 : pos);
                B[pos] = ((d & 511u) << 17) | sv[i];
            }
        }
        __syncthreads();
    }
}

__global__ __launch_bounds__(256)
void csr_build2_kernel(const unsigned* __restrict__ B, const int* __restrict__ gbase,
                       int* __restrict__ degc, int* __restrict__ offs,
                       float* __restrict__ dinv, int* __restrict__ csr,
                       int n_edges, int n_nodes) {
    __shared__ int cnt[512];
    __shared__ int scn[512];
    __shared__ int cur[512];
    const int b = blockIdx.x, t = threadIdx.x;
    cnt[t] = 0; cnt[t + 256] = 0;
    __syncthreads();
    const int lo = gbase[b], hi = gbase[b + 1];
    for (int i = lo + t; i < hi; i += 256) {
        unsigned v = B[i];
        atomicAdd(&cnt[v >> 17], 1);
    }
    __syncthreads();
    scn[t] = cnt[t]; scn[t + 256] = cnt[t + 256];
    __syncthreads();
    for (int off = 1; off < 512; off <<= 1) {
        int u0 = (t >= off) ? scn[t - off] : 0;
        int u1 = (t + 256 >= off) ? scn[t + 256 - off] : 0;
        __syncthreads();
        scn[t] += u0; scn[t + 256] += u1;
        __syncthreads();
    }
    const int base = gbase[b];
    int e0 = base + scn[t] - cnt[t];
    int e1 = base + scn[t + 256] - cnt[t + 256];
    cur[t] = e0; cur[t + 256] = e1;
    int n0 = b * 512 + t, n1 = n0 + 256;
    if (n0 < n_nodes) {
        degc[n0] = cnt[t]; offs[n0] = e0;
        dinv[n0] = 1.0f / fmaxf((float)cnt[t], 1.0f);
    }
    if (n1 < n_nodes) {
        degc[n1] = cnt[t + 256]; offs[n1] = e1;
        dinv[n1] = 1.0f / fmaxf((float)cnt[t + 256], 1.0f);
    }
    __syncthreads();
    for (int i = lo + t; i < hi; i += 256) {
        unsigned v = B[i];
        int pos = atomicAdd(&cur[v >> 17], 1);
        pos = pos < 0 ? 0 : (pos >= n_edges ? n_edges - 1 : pos);
        csr[pos] = (int)(v & 0x1FFFFu);
    }
}

// ---------------------------------------------------------------------------
// R4-proven FUSED gather+GEMM per layer. Per tile of 16 contiguous nodes: the
// 16 lane-groups run the proven R3 gather loop (1 node/group, lane u owns
// feats 4u..4u+3), stage the 16x64 agg tile in LDS (rows padded to 72 ->
// <=2-way bank conflict), sync, then the 4 waves each MFMA one 16-column
// tile using the PROVEN fragment mapping (A row=r16 k=ks*32+quad*8 /
// B f=ct*16+r16 / C row=quad*4+rg col=ct*16+r16).
// ---------------------------------------------------------------------------
__global__ __launch_bounds__(256)
void fused_l1_kernel(const __bf16* __restrict__ xb,
                     const int* __restrict__ offs, const int* __restrict__ degc,
                     const float* __restrict__ dinv, const int* __restrict__ csr,
                     const __bf16* __restrict__ Bl, const __bf16* __restrict__ Br,
                     const float* __restrict__ bias,
                     __bf16* __restrict__ hout, int n_nodes) {
    const int t = threadIdx.x, lane = t & 63, wave = t >> 6;
    const int quad = lane >> 4, r16 = lane & 15;
    const int grp = t >> 4, u = t & 15;          // gather role: 16 groups/block
    // per-wave B fragments for column-tile ct = wave
    bf16x8 bl[2], br[2];
    #pragma unroll
    for (int ks = 0; ks < 2; ++ks) {
        int f = wave * 16 + r16, k = ks * 32 + quad * 8;
        bl[ks] = *(const bf16x8*)(Bl + f * 64 + k);
        br[ks] = *(const bf16x8*)(Br + f * 64 + k);
    }
    const float bv = bias[wave * 16 + r16];
    __shared__ __bf16 sAgg[16][72];              // padded: 144B row stride
    const int ntiles = (n_nodes + 15) >> 4;
    for (int tile = blockIdx.x; tile < ntiles; tile += gridDim.x) {
        const int n = tile * 16 + grp;
        const bool act = n < n_nodes;
        float a0 = 0.f, a1 = 0.f, a2 = 0.f, a3 = 0.f, di = 1.f;
        if (act) {
            int rs = offs[n], cnt = degc[n];
            di = dinv[n];
            int idx = (u < cnt) ? (int)__builtin_nontemporal_load(&csr[rs + u]) : 0;
            int c = 0;
            while (true) {
                idx = idx < 0 ? 0 : (idx >= n_nodes ? n_nodes - 1 : idx);
                int sj[16];
                #pragma unroll
                for (int j = 0; j < 16; ++j) sj[j] = __shfl(idx, j, 16);
                bf16x4 v[16];
                #pragma unroll
                for (int j = 0; j < 16; ++j)
                    v[j] = ((const bf16x4*)xb)[(size_t)sj[j] * 16 + u];
                #pragma unroll
                for (int j = 0; j < 16; ++j) {
                    float m = (c + j < cnt) ? 1.f : 0.f;
                    a0 = fmaf(m, (float)v[j].x, a0);
                    a1 = fmaf(m, (float)v[j].y, a1);
                    a2 = fmaf(m, (float)v[j].z, a2);
                    a3 = fmaf(m, (float)v[j].w, a3);
                }
                c += 16;
                if (c >= cnt) break;
                idx = (u < cnt - c) ? (int)__builtin_nontemporal_load(&csr[rs + c + u]) : 0;
            }
        }
        bf16x4 o;
        o.x = (__bf16)(a0 * di); o.y = (__bf16)(a1 * di);
        o.z = (__bf16)(a2 * di); o.w = (__bf16)(a3 * di);
        *(bf16x4*)(&sAgg[grp][u * 4]) = o;       // same rounding as old agg path
        __syncthreads();
        // ---- MFMA phase (ct = wave) ----
        const int m0 = tile * 16;
        int mrow = m0 + r16; if (mrow >= n_nodes) mrow = n_nodes - 1;
        bf16x8 ag[2], ax[2];
        #pragma unroll
        for (int ks = 0; ks < 2; ++ks) {
            ag[ks] = *(const bf16x8*)(&sAgg[r16][ks * 32 + quad * 8]);
            ax[ks] = *(const bf16x8*)(xb + (size_t)mrow * 64 + ks * 32 + quad * 8);
        }
        f32x4 acc = {0.f, 0.f, 0.f, 0.f};
        acc = __builtin_amdgcn_mfma_f32_16x16x32_bf16(ag[0], bl[0], acc, 0, 0, 0);
        acc = __builtin_amdgcn_mfma_f32_16x16x32_bf16(ag[1], bl[1], acc, 0, 0, 0);
        acc = __builtin_amdgcn_mfma_f32_16x16x32_bf16(ax[0], br[0], acc, 0, 0, 0);
        acc = __builtin_amdgcn_mfma_f32_16x16x32_bf16(ax[1], br[1], acc, 0, 0, 0);
        const int col = wave * 16 + r16;
        #pragma unroll
        for (int rg = 0; rg < 4; ++rg) {
            int row = m0 + quad * 4 + rg;
            if (row < n_nodes) {
                float ov = acc[rg] + bv;
                hout[(size_t)row * 64 + col] = (__bf16)fmaxf(ov, 0.f);
            }
        }
        __syncthreads();                          // protect sAgg before next tile
    }
}

__global__ __launch_bounds__(256)
void fused_l2_kernel(const __bf16* __restrict__ hb,
                     const int* __restrict__ offs, const int* __restrict__ degc,
                     const float* __restrict__ dinv, const int* __restrict__ csr,
                     const __bf16* __restrict__ Bl, const __bf16* __restrict__ Br,
                     const float* __restrict__ bias,
                     float* __restrict__ out, int n_nodes) {
    const int t = threadIdx.x, lane = t & 63, wave = t >> 6;
    const int quad = lane >> 4, r16 = lane & 15;
    const int grp = t >> 4, u = t & 15;
    bf16x8 bl[2], br[2];
    #pragma unroll
    for (int ks = 0; ks < 2; ++ks) {
        int f = wave * 16 + r16, k = ks * 32 + quad * 8;
        bl[ks] = *(const bf16x8*)(Bl + f * 64 + k);
        br[ks] = *(const bf16x8*)(Br + f * 64 + k);
    }
    const float bv = bias[wave * 16 + r16];
    __shared__ __bf16 sAgg[16][72];
    const int ntiles = (n_nodes + 15) >> 4;
    for (int tile = blockIdx.x; tile < ntiles; tile += gridDim.x) {
        const int n = tile * 16 + grp;
        const bool act = n < n_nodes;
        float a0 = 0.f, a1 = 0.f, a2 = 0.f, a3 = 0.f, di = 1.f;
        if (act) {
            int rs = offs[n], cnt = degc[n];
            di = dinv[n];
            int idx = (u < cnt) ? (int)__builtin_nontemporal_load(&csr[rs + u]) : 0;
            int c = 0;
            while (true) {
                idx = idx < 0 ? 0 : (idx >= n_nodes ? n_nodes - 1 : idx);
                int sj[16];
                #pragma unroll
                for (int j = 0; j < 16; ++j) sj[j] = __shfl(idx, j, 16);
                bf16x4 v[16];
                #pragma unroll
                for (int j = 0; j < 16; ++j)
                    v[j] = ((const bf16x4*)hb)[(size_t)sj[j] * 16 + u];
                #pragma unroll
                for (int j = 0; j < 16; ++j) {
                    float m = (c + j < cnt) ? 1.f : 0.f;
                    a0 = fmaf(m, (float)v[j].x, a0);
                    a1 = fmaf(m, (float)v[j].y, a1);
                    a2 = fmaf(m, (float)v[j].z, a2);
                    a3 = fmaf(m, (float)v[j].w, a3);
                }
                c += 16;
                if (c >= cnt) break;
                idx = (u < cnt - c) ? (int)__builtin_nontemporal_load(&csr[rs + c + u]) : 0;
            }
        }
        bf16x4 o;
        o.x = (__bf16)(a0 * di); o.y = (__bf16)(a1 * di);
        o.z = (__bf16)(a2 * di); o.w = (__bf16)(a3 * di);
        *(bf16x4*)(&sAgg[grp][u * 4]) = o;
        __syncthreads();
        const int m0 = tile * 16;
        int mrow = m0 + r16; if (mrow >= n_nodes) mrow = n_nodes - 1;
        bf16x8 ag[2], ah[2];
        #pragma unroll
        for (int ks = 0; ks < 2; ++ks) {
            ag[ks] = *(const bf16x8*)(&sAgg[r16][ks * 32 + quad * 8]);
            ah[ks] = *(const bf16x8*)(hb + (size_t)mrow * 64 + ks * 32 + quad * 8);
        }
        f32x4 acc = {0.f, 0.f, 0.f, 0.f};
        acc = __builtin_amdgcn_mfma_f32_16x16x32_bf16(ag[0], bl[0], acc, 0, 0, 0);
        acc = __builtin_amdgcn_mfma_f32_16x16x32_bf16(ag[1], bl[1], acc, 0, 0, 0);
        acc = __builtin_amdgcn_mfma_f32_16x16x32_bf16(ah[0], br[0], acc, 0, 0, 0);
        acc = __builtin_amdgcn_mfma_f32_16x16x32_bf16(ah[1], br[1], acc, 0, 0, 0);
        const int col = wave * 16 + r16;
        #pragma unroll
        for (int rg = 0; rg < 4; ++rg) {
            int row = m0 + quad * 4 + rg;
            if (row < n_nodes) out[(size_t)row * 64 + col] = acc[rg] + bv;
        }
        __syncthreads();
    }
}

// ---------------------------------------------------------------------------
// Scans (T3/T4 paths)
// ---------------------------------------------------------------------------
__global__ __launch_bounds__(256)
void scan_partial_kernel(const int* __restrict__ degc, int* __restrict__ part, int n_nodes) {
    __shared__ int sh[256];
    int i = blockIdx.x * 256 + threadIdx.x;
    sh[threadIdx.x] = (i < n_nodes) ? degc[i] : 0;
    __syncthreads();
    for (int off = 128; off > 0; off >>= 1) {
        if (threadIdx.x < off) sh[threadIdx.x] += sh[threadIdx.x + off];
        __syncthreads();
    }
    if (threadIdx.x == 0) part[blockIdx.x] = sh[0];
}

__global__ void scan_top_kernel(int* __restrict__ part, int nparts) {
    __shared__ int sh[512];
    int t = threadIdx.x;
    int v = (t < nparts) ? part[t] : 0;
    sh[t] = v;
    __syncthreads();
    for (int off = 1; off < 512; off <<= 1) {
        int u = (t >= off) ? sh[t - off] : 0;
        __syncthreads();
        sh[t] += u;
        __syncthreads();
    }
    if (t < nparts) part[t] = sh[t] - v;   // exclusive
}

__global__ __launch_bounds__(256)
void scan_final_kernel(const int* __restrict__ degc, const int* __restrict__ part,
                       int* __restrict__ offs, float* __restrict__ deg_inv, int n_nodes) {
    __shared__ int sh[256];
    int t = threadIdx.x;
    int i = blockIdx.x * 256 + t;
    int v = (i < n_nodes) ? degc[i] : 0;
    sh[t] = v;
    __syncthreads();
    for (int off = 1; off < 256; off <<= 1) {
        int u = (t >= off) ? sh[t - off] : 0;
        __syncthreads();
        sh[t] += u;
        __syncthreads();
    }
    if (i < n_nodes) {
        offs[i]    = sh[t] - v + part[blockIdx.x];
        deg_inv[i] = 1.0f / fmaxf((float)v, 1.0f);
    }
}

// ---------------------------------------------------------------------------
// T3 path: global-atomic hist + cursor scatter.
// ---------------------------------------------------------------------------
__global__ __launch_bounds__(256)
void hist_kernel(const void* __restrict__ ei, const int* __restrict__ flagp,
                 int* __restrict__ degc, int n_edges, int n_nodes) {
    int e = blockIdx.x * 256 + threadIdx.x;
    if (e >= n_edges) return;
    int d = load_idx_clamped(ei, (long long)n_edges + e, *flagp, n_nodes);
    atomicAdd(&degc[d], 1);
}

__global__ __launch_bounds__(256)
void csr_scatter_kernel(const void* __restrict__ ei, const int* __restrict__ flagp,
                        const int* __restrict__ offs, int* __restrict__ cursor,
                        int* __restrict__ csr, int n_edges, int n_nodes) {
    int e = blockIdx.x * 256 + threadIdx.x;
    if (e >= n_edges) return;
    int is64 = *flagp;
    int s = load_idx_clamped(ei, e, is64, n_nodes);
    int d = load_idx_clamped(ei, (long long)n_edges + e, is64, n_nodes);
    int pos = offs[d] + atomicAdd(&cursor[d], 1);
    pos = pos < 0 ? 0 : (pos >= n_edges ? n_edges - 1 : pos);
    csr[pos] = s;
}

// ---------------------------------------------------------------------------
// Casts (T3 fallback path)
// ---------------------------------------------------------------------------
__global__ __launch_bounds__(256)
void cast_w_kernel(const float* __restrict__ a, const float* __restrict__ b,
                   const float* __restrict__ c, const float* __restrict__ d,
                   __bf16* __restrict__ o) {
    int i = blockIdx.x * 256 + threadIdx.x;
    if (i < FEAT * FEAT) {
        o[i]         = (__bf16)a[i];
        o[4096 + i]  = (__bf16)b[i];
        o[8192 + i]  = (__bf16)c[i];
        o[12288 + i] = (__bf16)d[i];
    }
}

// ---------------------------------------------------------------------------
// Standalone gather kernels (T3 fallback path; unchanged, proven).
// ---------------------------------------------------------------------------
__global__ __launch_bounds__(256)
void gather_bf16_kernel(const __bf16* __restrict__ hin, const int* __restrict__ offs,
                        const int* __restrict__ degc, const float* __restrict__ dinv,
                        const int* __restrict__ csr, __bf16* __restrict__ agg,
                        int n_nodes) {
    const int t = threadIdx.x, u = t & 15;
    const int g0 = blockIdx.x * 16 + (t >> 4);
    const int ng = gridDim.x * 16;
    if (g0 >= n_nodes) return;
    int rs = offs[g0], cnt = degc[g0];
    float di = dinv[g0];
    int idx = (u < cnt) ? (int)__builtin_nontemporal_load(&csr[rs + u]) : 0;
    for (int n = g0; n < n_nodes; n += ng) {
        const int nn = n + ng;
        int rs2 = 0, cnt2 = 0;
        float di2 = 1.0f;
        if (nn < n_nodes) { rs2 = offs[nn]; cnt2 = degc[nn]; di2 = dinv[nn]; }
        float a0 = 0.f, a1 = 0.f, a2 = 0.f, a3 = 0.f;
        int c = 0;
        while (true) {
            idx = idx < 0 ? 0 : (idx >= n_nodes ? n_nodes - 1 : idx);
            int sj[16];
            #pragma unroll
            for (int j = 0; j < 16; ++j) sj[j] = __shfl(idx, j, 16);
            bf16x4 v[16];
            #pragma unroll
            for (int j = 0; j < 16; ++j)
                v[j] = ((const bf16x4*)hin)[(size_t)sj[j] * 16 + u];
            #pragma unroll
            for (int j = 0; j < 16; ++j) {
                float m = (c + j < cnt) ? 1.f : 0.f;
                a0 = fmaf(m, (float)v[j].x, a0);
                a1 = fmaf(m, (float)v[j].y, a1);
                a2 = fmaf(m, (float)v[j].z, a2);
                a3 = fmaf(m, (float)v[j].w, a3);
            }
            c += 16;
            if (c >= cnt) break;
            idx = (u < cnt - c) ? (int)__builtin_nontemporal_load(&csr[rs + c + u]) : 0;
        }
        idx = (nn < n_nodes && u < cnt2)
                  ? (int)__builtin_nontemporal_load(&csr[rs2 + u]) : 0;
        bf16x4 o;
        o.x = (__bf16)(a0 * di); o.y = (__bf16)(a1 * di);
        o.z = (__bf16)(a2 * di); o.w = (__bf16)(a3 * di);
        ((bf16x4*)agg)[(size_t)n * 16 + u] = o;
        rs = rs2; cnt = cnt2; di = di2;
    }
}

__global__ __launch_bounds__(256)
void gather_f32_kernel(const float* __restrict__ xin, const int* __restrict__ offs,
                       const int* __restrict__ degc, const float* __restrict__ dinv,
                       const int* __restrict__ csr, __bf16* __restrict__ agg,
                       int n_nodes) {
    const int t = threadIdx.x, lane = t & 63, g = lane >> 4, u = lane & 15;
    const int gw = blockIdx.x * 4 + (t >> 6), nw = gridDim.x * 4;
    for (int n = gw; n < n_nodes; n += nw) {
        int rs = offs[n], cnt = degc[n];
        float a0 = 0.f, a1 = 0.f, a2 = 0.f, a3 = 0.f;
        for (int c = 0; c < cnt; c += 64) {
            int chunk = min(64, cnt - c);
            int myid = (lane < chunk) ? (int)__builtin_nontemporal_load(&csr[rs + c + lane]) : 0;
            myid = myid < 0 ? 0 : (myid >= n_nodes ? n_nodes - 1 : myid);
            for (int q = 0; q < chunk; q += 16) {
                int q0 = q + g, q1 = q + g + 4, q2 = q + g + 8, q3 = q + g + 12;
                int s0 = __shfl(myid, q0), s1 = __shfl(myid, q1);
                int s2 = __shfl(myid, q2), s3 = __shfl(myid, q3);
                float m0 = (q0 < chunk) ? 1.f : 0.f;
                float m1 = (q1 < chunk) ? 1.f : 0.f;
                float m2 = (q2 < chunk) ? 1.f : 0.f;
                float m3 = (q3 < chunk) ? 1.f : 0.f;
                float4 v0 = ((const float4*)xin)[(size_t)s0 * 16 + u];
                float4 v1 = ((const float4*)xin)[(size_t)s1 * 16 + u];
                float4 v2 = ((const float4*)xin)[(size_t)s2 * 16 + u];
                float4 v3 = ((const float4*)xin)[(size_t)s3 * 16 + u];
                a0 = fmaf(m0, v0.x, a0); a1 = fmaf(m0, v0.y, a1);
                a2 = fmaf(m0, v0.z, a2); a3 = fmaf(m0, v0.w, a3);
                a0 = fmaf(m1, v1.x, a0); a1 = fmaf(m1, v1.y, a1);
                a2 = fmaf(m1, v1.z, a2); a3 = fmaf(m1, v1.w, a3);
                a0 = fmaf(m2, v2.x, a0); a1 = fmaf(m2, v2.y, a1);
                a2 = fmaf(m2, v2.z, a2); a3 = fmaf(m2, v2.w, a3);
                a0 = fmaf(m3, v3.x, a0); a1 = fmaf(m3, v3.y, a1);
                a2 = fmaf(m3, v3.z, a2); a3 = fmaf(m3, v3.w, a3);
            }
        }
        a0 += __shfl_xor(a0, 16); a1 += __shfl_xor(a1, 16);
        a2 += __shfl_xor(a2, 16); a3 += __shfl_xor(a3, 16);
        a0 += __shfl_xor(a0, 32); a1 += __shfl_xor(a1, 32);
        a2 += __shfl_xor(a2, 32); a3 += __shfl_xor(a3, 32);
        if (g == 0) {
            float di = dinv[n];
            bf16x4 o;
            o.x = (__bf16)(a0 * di); o.y = (__bf16)(a1 * di);
            o.z = (__bf16)(a2 * di); o.w = (__bf16)(a3 * di);
            ((bf16x4*)agg)[(size_t)n * 16 + u] = o;
        }
    }
}

// ---------------------------------------------------------------------------
// Standalone MFMA GEMMs (T3 fallback path; unchanged, proven).
// ---------------------------------------------------------------------------
__global__ __launch_bounds__(256)
void gemm_l1_kernel(const __bf16* __restrict__ Ag, const float* __restrict__ xin,
                    const __bf16* __restrict__ Bl, const __bf16* __restrict__ Br,
                    const float* __restrict__ bias,
                    __bf16* __restrict__ hout, int n_nodes) {
    const int t = threadIdx.x, lane = t & 63;
    const int quad = lane >> 4, r16 = lane & 15;
    bf16x8 bl[2][4], br[2][4];
    #pragma unroll
    for (int ks = 0; ks < 2; ++ks)
        #pragma unroll
        for (int ct = 0; ct < 4; ++ct) {
            int f = ct * 16 + r16, k = ks * 32 + quad * 8;
            bl[ks][ct] = *(const bf16x8*)(Bl + f * 64 + k);
            br[ks][ct] = *(const bf16x8*)(Br + f * 64 + k);
        }
    const int m0 = (blockIdx.x * 4 + (t >> 6)) * 16;
    if (m0 >= n_nodes) return;
    int mrow = m0 + r16; if (mrow >= n_nodes) mrow = n_nodes - 1;
    bf16x8 ag[2], ax[2];
    #pragma unroll
    for (int ks = 0; ks < 2; ++ks) {
        ag[ks] = *(const bf16x8*)(Ag + (size_t)mrow * 64 + ks * 32 + quad * 8);
        const float* xr = xin + (size_t)mrow * 64 + ks * 32 + quad * 8;
        float4 p = *(const float4*)xr;
        float4 q = *(const float4*)(xr + 4);
        union { bf16x8 v; __bf16 e[8]; } U;
        U.e[0] = (__bf16)p.x; U.e[1] = (__bf16)p.y; U.e[2] = (__bf16)p.z; U.e[3] = (__bf16)p.w;
        U.e[4] = (__bf16)q.x; U.e[5] = (__bf16)q.y; U.e[6] = (__bf16)q.z; U.e[7] = (__bf16)q.w;
        ax[ks] = U.v;
    }
    #pragma unroll
    for (int ct = 0; ct < 4; ++ct) {
        f32x4 acc = {0.f, 0.f, 0.f, 0.f};
        acc = __builtin_amdgcn_mfma_f32_16x16x32_bf16(ag[0], bl[0][ct], acc, 0, 0, 0);
        acc = __builtin_amdgcn_mfma_f32_16x16x32_bf16(ag[1], bl[1][ct], acc, 0, 0, 0);
        acc = __builtin_amdgcn_mfma_f32_16x16x32_bf16(ax[0], br[0][ct], acc, 0, 0, 0);
        acc = __builtin_amdgcn_mfma_f32_16x16x32_bf16(ax[1], br[1][ct], acc, 0, 0, 0);
        int col = ct * 16 + r16;
        float bv = bias[col];
        #pragma unroll
        for (int rg = 0; rg < 4; ++rg) {
            int n = m0 + quad * 4 + rg;
            if (n < n_nodes) {
                float o = acc[rg] + bv;
                hout[(size_t)n * 64 + col] = (__bf16)fmaxf(o, 0.f);
            }
        }
    }
}

__global__ __launch_bounds__(256)
void gemm_l2_kernel(const __bf16* __restrict__ Ag, const __bf16* __restrict__ Ah,
                    const __bf16* __restrict__ Bl, const __bf16* __restrict__ Br,
                    const float* __restrict__ bias,
                    float* __restrict__ out, int n_nodes) {
    const int t = threadIdx.x, lane = t & 63;
    const int quad = lane >> 4, r16 = lane & 15;
    bf16x8 bl[2][4], br[2][4];
    #pragma unroll
    for (int ks = 0; ks < 2; ++ks)
        #pragma unroll
        for (int ct = 0; ct < 4; ++ct) {
            int f = ct * 16 + r16, k = ks * 32 + quad * 8;
            bl[ks][ct] = *(const bf16x8*)(Bl + f * 64 + k);
            br[ks][ct] = *(const bf16x8*)(Br + f * 64 + k);
        }
    const int m0 = (blockIdx.x * 4 + (t >> 6)) * 16;
    if (m0 >= n_nodes) return;
    int mrow = m0 + r16; if (mrow >= n_nodes) mrow = n_nodes - 1;
    bf16x8 ag[2], ah[2];
    #pragma unroll
    for (int ks = 0; ks < 2; ++ks) {
        ag[ks] = *(const bf16x8*)(Ag + (size_t)mrow * 64 + ks * 32 + quad * 8);
        ah[ks] = *(const bf16x8*)(Ah + (size_t)mrow * 64 + ks * 32 + quad * 8);
    }
    #pragma unroll
    for (int ct = 0; ct < 4; ++ct) {
        f32x4 acc = {0.f, 0.f, 0.f, 0.f};
        acc = __builtin_amdgcn_mfma_f32_16x16x32_bf16(ag[0], bl[0][ct], acc, 0, 0, 0);
        acc = __builtin_amdgcn_mfma_f32_16x16x32_bf16(ag[1], bl[1][ct], acc, 0, 0, 0);
        acc = __builtin_amdgcn_mfma_f32_16x16x32_bf16(ah[0], br[0][ct], acc, 0, 0, 0);
        acc = __builtin_amdgcn_mfma_f32_16x16x32_bf16(ah[1], br[1][ct], acc, 0, 0, 0);
        int col = ct * 16 + r16;
        float bv = bias[col];
        #pragma unroll
        for (int rg = 0; rg < 4; ++rg) {
            int n = m0 + quad * 4 + rg;
            if (n < n_nodes) out[(size_t)n * 64 + col] = acc[rg] + bv;
        }
    }
}

// ---------------------------------------------------------------------------
// T4 fallback: fused LDS kernels (unchanged).
// ---------------------------------------------------------------------------
__global__ __launch_bounds__(256)
void sage_fused_l1_kernel(const float* __restrict__ xin,
                          const int* __restrict__ offs, const int* __restrict__ degc,
                          const float* __restrict__ deg_inv, const int* __restrict__ csr,
                          const float* __restrict__ Wl, const float* __restrict__ bias,
                          const float* __restrict__ Wr,
                          __bf16* __restrict__ hout, int n_nodes) {
    __shared__ float WlT[FEAT * 65], WrT[FEAT * 65], bsh[FEAT];
    __shared__ float aggS[4][FEAT], selfS[4][FEAT];
    const int t = threadIdx.x;
    #pragma unroll
    for (int p = 0; p < 16; ++p) {
        int i = t + p * 256, j = i >> 6, k = i & 63;
        WlT[k * 65 + j] = Wl[i];
        WrT[k * 65 + j] = Wr[i];
    }
    if (t < FEAT) bsh[t] = bias[t];
    __syncthreads();
    const int w = t >> 6, f = t & 63;
    const int n_groups = (n_nodes + 3) >> 2;
    for (int g = blockIdx.x; g < n_groups; g += gridDim.x) {
        int n = g * 4 + w;
        bool act = (n < n_nodes);
        if (act) {
            int rs = offs[n], cnt = degc[n];
            float acc = 0.f;
            for (int c = 0; c < cnt; c += 64) {
                int chunk = min(64, cnt - c);
                int myid = (f < chunk) ? csr[rs + c + f] : 0;
                #pragma unroll 4
                for (int q = 0; q < chunk; ++q) {
                    int s = __shfl(myid, q);
                    acc += xin[(long long)s * FEAT + f];
                }
            }
            aggS[w][f]  = acc * deg_inv[n];
            selfS[w][f] = xin[(long long)n * FEAT + f];
        }
        __syncthreads();
        if (act) {
            float o = bsh[f];
            #pragma unroll
            for (int k = 0; k < FEAT; ++k) {
                o = fmaf(aggS[w][k],  WlT[k * 65 + f], o);
                o = fmaf(selfS[w][k], WrT[k * 65 + f], o);
            }
            o = fmaxf(o, 0.f);
            hout[(long long)n * FEAT + f] = (__bf16)o;
        }
        __syncthreads();
    }
}

__global__ __launch_bounds__(256)
void sage_fused_l2_kernel(const __bf16* __restrict__ hin,
                          const int* __restrict__ offs, const int* __restrict__ degc,
                          const float* __restrict__ deg_inv, const int* __restrict__ csr,
                          const float* __restrict__ Wl, const float* __restrict__ bias,
                          const float* __restrict__ Wr,
                          float* __restrict__ out, int n_nodes) {
    __shared__ float WlT[FEAT * 65], WrT[FEAT * 65], bsh[FEAT];
    __shared__ float aggS[4][FEAT], selfS[4][FEAT];
    const int t = threadIdx.x;
    #pragma unroll
    for (int p = 0; p < 16; ++p) {
        int i = t + p * 256, j = i >> 6, k = i & 63;
        WlT[k * 65 + j] = Wl[i];
        WrT[k * 65 + j] = Wr[i];
    }
    if (t < FEAT) bsh[t] = bias[t];
    __syncthreads();
    const int w = t >> 6, f = t & 63;
    const int n_groups = (n_nodes + 3) >> 2;
    for (int g = blockIdx.x; g < n_groups; g += gridDim.x) {
        int n = g * 4 + w;
        bool act = (n < n_nodes);
        if (act) {
            int rs = offs[n], cnt = degc[n];
            float acc = 0.f;
            for (int c = 0; c < cnt; c += 64) {
                int chunk = min(64, cnt - c);
                int myid = (f < chunk) ? csr[rs + c + f] : 0;
                #pragma unroll 4
                for (int q = 0; q < chunk; ++q) {
                    int s = __shfl(myid, q);
                    acc += (float)hin[(long long)s * FEAT + f];
                }
            }
            aggS[w][f]  = acc * deg_inv[n];
            selfS[w][f] = (float)hin[(long long)n * FEAT + f];
        }
        __syncthreads();
        if (act) {
            float o = bsh[f];
            #pragma unroll
            for (int k = 0; k < FEAT; ++k) {
                o = fmaf(aggS[w][k],  WlT[k * 65 + f], o);
                o = fmaf(selfS[w][k], WrT[k * 65 + f], o);
            }
            out[(long long)n * FEAT + f] = o;
        }
        __syncthreads();
    }
}

// ---------------------------------------------------------------------------
// Launch
// ---------------------------------------------------------------------------
extern "C" void kernel_launch(void* const* d_in, const int* in_sizes, int n_in,
                              void* d_out, int out_size, void* d_ws, size_t ws_size,
                              hipStream_t stream) {
    const float* x   = (const float*)d_in[0];
    const void*  ei  = d_in[1];
    const float* W1l = (const float*)d_in[2];
    const float* b1  = (const float*)d_in[3];
    const float* W1r = (const float*)d_in[4];
    const float* W2l = (const float*)d_in[5];
    const float* b2  = (const float*)d_in[6];
    const float* W2r = (const float*)d_in[7];
    float* out = (float*)d_out;

    const int n_nodes = in_sizes[0] / FEAT;
    const int n_edges = in_sizes[1] / 2;
    const int nparts  = (n_nodes + 255) / 256;     // <= 512
    const int egrid   = (n_edges + 255) / 256;
    const int NB      = (n_nodes + 511) >> 9;      // buckets of 512 nodes

    char* ws = (char*)d_ws;
    auto al = [](size_t v) { return (v + 255) & ~(size_t)255; };

    // ---- T1 layout (two-level counting sort; agg buffer removed in R4) ----
    size_t o = 0;
    int*      flag  = (int*)(ws + o);      o += 256;
    int*      degc  = (int*)(ws + o);      o += al((size_t)n_nodes * 4);
    float*    dinv  = (float*)(ws + o);    o += al((size_t)n_nodes * 4);
    int*      offs  = (int*)(ws + o);      o += al((size_t)n_nodes * 4);
    int*      gcnt  = (int*)(ws + o);      o += al(512 * 4);
    int*      gbase = (int*)(ws + o);      o += al(513 * 4);
    int*      gcur  = (int*)(ws + o);      o += al(512 * 4);
    unsigned* B     = (unsigned*)(ws + o); o += al((size_t)n_edges * 4);
    int*      csr   = (int*)(ws + o);      o += al((size_t)n_edges * 4);
    __bf16*   xb    = (__bf16*)(ws + o);   o += al((size_t)n_nodes * FEAT * 2);
    __bf16*   wb    = (__bf16*)(ws + o);   o += al((size_t)4 * FEAT * FEAT * 2);
    __bf16*   h     = (__bf16*)(ws + o);   o += al((size_t)n_nodes * FEAT * 2);
    const size_t needT1 = o;

    // ---- T3 layout (proven fallback) ----
    size_t o3 = 0;
    int*    flag3   = (int*)(ws + o3);    o3 += 256;
    int*    degc3   = (int*)(ws + o3);    o3 += al((size_t)n_nodes * 4);
    float*  dinv3   = (float*)(ws + o3);  o3 += al((size_t)n_nodes * 4);
    int*    offs3   = (int*)(ws + o3);    o3 += al((size_t)n_nodes * 4);
    int*    cursor3 = (int*)(ws + o3);    o3 += al((size_t)n_nodes * 4);
    int*    part3   = (int*)(ws + o3);    o3 += al(2048);
    int*    csr3    = (int*)(ws + o3);    o3 += al((size_t)n_edges * 4);
    const size_t commonEnd3 = o3;
    __bf16* wb3  = (__bf16*)(ws + o3);    o3 += al((size_t)4 * FEAT * FEAT * 2);
    __bf16* agg3 = (__bf16*)(ws + o3);    o3 += al((size_t)n_nodes * FEAT * 2);
    __bf16* h3   = (__bf16*)(ws + o3);    o3 += al((size_t)n_nodes * FEAT * 2);
    const size_t needT3 = o3;

    const int n4 = n_nodes * FEAT / 4;
    const int mgrid = (n_nodes + 63) / 64;
    const int ggrid = 2048;
    const int ntiles = (n_edges + 4095) >> 12;
    const int ftiles = (n_nodes + 15) >> 4;
    const int fgrid2 = ftiles < 2048 ? ftiles : 2048;

    if (ws_size >= needT1 && n_nodes <= 131072) {
        detect_castw_kernel<<<17, 256, 0, stream>>>((const unsigned*)ei, flag, gcnt,
                                                    W1l, W1r, W2l, W2r, wb);
        bucket_count_castx_kernel<<<1536, 256, 0, stream>>>(ei, flag, gcnt,
                                                            x, xb, n4, n_edges, n_nodes);
        bucket_scan_kernel<<<1, 512, 0, stream>>>(gcnt, gbase, gcur, n_edges);
        multisplit_kernel<<<ntiles, 256, 0, stream>>>(ei, flag, gcur, B, n_edges, n_nodes);
        csr_build2_kernel<<<NB, 256, 0, stream>>>(B, gbase, degc, offs, dinv, csr, n_edges, n_nodes);
        fused_l1_kernel<<<fgrid2, 256, 0, stream>>>(xb, offs, degc, dinv, csr,
                                                    wb, wb + 4096, b1, h, n_nodes);
        fused_l2_kernel<<<fgrid2, 256, 0, stream>>>(h, offs, degc, dinv, csr,
                                                    wb + 8192, wb + 12288, b2, out, n_nodes);
    } else if (ws_size >= needT3) {
        zero2_kernel<<<nparts, 256, 0, stream>>>(degc3, cursor3, n_nodes);
        detect_idx_kernel<<<1, 256, 0, stream>>>((const unsigned*)ei, flag3, part3);
        hist_kernel<<<egrid, 256, 0, stream>>>(ei, flag3, degc3, n_edges, n_nodes);
        scan_partial_kernel<<<nparts, 256, 0, stream>>>(degc3, part3, n_nodes);
        scan_top_kernel<<<1, 512, 0, stream>>>(part3, nparts);
        scan_final_kernel<<<nparts, 256, 0, stream>>>(degc3, part3, offs3, dinv3, n_nodes);
        csr_scatter_kernel<<<egrid, 256, 0, stream>>>(ei, flag3, offs3, cursor3, csr3, n_edges, n_nodes);
        cast_w_kernel<<<16, 256, 0, stream>>>(W1l, W1r, W2l, W2r, wb3);
        gather_f32_kernel<<<ggrid, 256, 0, stream>>>(x, offs3, degc3, dinv3, csr3, agg3, n_nodes);
        gemm_l1_kernel<<<mgrid, 256, 0, stream>>>(agg3, x, wb3, wb3 + 4096, b1, h3, n_nodes);
        gather_bf16_kernel<<<ggrid, 256, 0, stream>>>(h3, offs3, degc3, dinv3, csr3, agg3, n_nodes);
        gemm_l2_kernel<<<mgrid, 256, 0, stream>>>(agg3, h3, wb3 + 8192, wb3 + 12288, b2, out, n_nodes);
    } else {
        __bf16* hf = (__bf16*)(ws + commonEnd3);
        zero2_kernel<<<nparts, 256, 0, stream>>>(degc3, cursor3, n_nodes);
        detect_idx_kernel<<<1, 256, 0, stream>>>((const unsigned*)ei, flag3, part3);
        hist_kernel<<<egrid, 256, 0, stream>>>(ei, flag3, degc3, n_edges, n_nodes);
        scan_partial_kernel<<<nparts, 256, 0, stream>>>(degc3, part3, n_nodes);
        scan_top_kernel<<<1, 512, 0, stream>>>(part3, nparts);
        scan_final_kernel<<<nparts, 256, 0, stream>>>(degc3, part3, offs3, dinv3, n_nodes);
        csr_scatter_kernel<<<egrid, 256, 0, stream>>>(ei, flag3, offs3, cursor3, csr3, n_edges, n_nodes);
        const int n_groups = (n_nodes + 3) / 4;
        const int fgrid = n_groups < 4096 ? n_groups : 4096;
        sage_fused_l1_kernel<<<fgrid, 256, 0, stream>>>(x, offs3, degc3, dinv3, csr3,
                                                        W1l, b1, W1r, hf, n_nodes);
        sage_fused_l2_kernel<<<fgrid, 256, 0, stream>>>(hf, offs3, degc3, dinv3, csr3,
                                                        W2l, b2, W2r, out, n_nodes);
    }
}

// Round 9
// 232.319 us; speedup vs baseline: 6.4095x; 1.0251x over previous
//
#include <hip/hip_runtime.h>
#include <hip/hip_bf16.h>

#define FEAT 64

typedef __bf16 bf16x8 __attribute__((ext_vector_type(8)));
typedef __bf16 bf16x4 __attribute__((ext_vector_type(4)));
typedef float  f32x4  __attribute__((ext_vector_type(4)));

// ---------------------------------------------------------------------------
// JOURNAL:
// R4/R8 = proven structure, 240.0/238.2us (noise +-2us). R6 chain edits
// (ticket scan + 256-node buckets) = genuine +15us regression. R5 edge-centric
// LDS atomics = 685us/layer, never again. Fused kernels are at the random-row
// service floor (85MB @ 2.3TB/s, 3 structures converged) -- at roofline.
// Chain ~143us vs ~30us traffic floor -> this round: single-variable probe,
// csr_build2 at 512 threads/block (1 node/thread, halves per-block serial
// work; 196 blocks < 256 CUs so block wall time is the kernel time).
// ---------------------------------------------------------------------------

// ---------------------------------------------------------------------------
// Zero kernel (hipMemsetAsync may execute at capture time -> poisoned replay).
// ---------------------------------------------------------------------------
__global__ __launch_bounds__(256)
void zero2_kernel(int* __restrict__ a, int* __restrict__ b, int n) {
    int i = blockIdx.x * 256 + threadIdx.x;
    if (i < n) { a[i] = 0; b[i] = 0; }
}

// ---------------------------------------------------------------------------
// detect + cast_w fused (block 0 sniffs int64-ness & zeroes gcnt;
// blocks 1..16 cast the 4 weight matrices).
// ---------------------------------------------------------------------------
__global__ void detect_castw_kernel(const unsigned* __restrict__ w, int* __restrict__ flag,
                                    int* __restrict__ zcnt,
                                    const float* __restrict__ a, const float* __restrict__ b,
                                    const float* __restrict__ c, const float* __restrict__ d,
                                    __bf16* __restrict__ o) {
    if (blockIdx.x == 0) {
        __shared__ int any_nz;
        if (threadIdx.x == 0) any_nz = 0;
        __syncthreads();
        if (w[2 * threadIdx.x + 1] != 0u) atomicOr(&any_nz, 1);  // first 2KB only
        zcnt[threadIdx.x] = 0;
        zcnt[threadIdx.x + 256] = 0;
        __syncthreads();
        if (threadIdx.x == 0) *flag = (any_nz == 0) ? 1 : 0;
    } else {
        int i = (blockIdx.x - 1) * 256 + threadIdx.x;
        if (i < FEAT * FEAT) {
            o[i]         = (__bf16)a[i];
            o[4096 + i]  = (__bf16)b[i];
            o[8192 + i]  = (__bf16)c[i];
            o[12288 + i] = (__bf16)d[i];
        }
    }
}

// T3-path detect (kept).
__global__ void detect_idx_kernel(const unsigned* __restrict__ w, int* __restrict__ flag,
                                  int* __restrict__ zcnt) {
    __shared__ int any_nz;
    if (threadIdx.x == 0) any_nz = 0;
    __syncthreads();
    if (w[2 * threadIdx.x + 1] != 0u) atomicOr(&any_nz, 1);
    zcnt[threadIdx.x] = 0;
    zcnt[threadIdx.x + 256] = 0;
    __syncthreads();
    if (threadIdx.x == 0) *flag = (any_nz == 0) ? 1 : 0;
}

// 4-byte index load: node ids are < 2^17, so for int64 input the high dword
// is always zero (sniffer-verified) -> read only the low dword.
__device__ __forceinline__ int load_idx_clamped(const void* ei, long long i, int is64, int n_nodes) {
    int v = is64 ? ((const int*)ei)[2 * i] : ((const int*)ei)[i];
    v = v < 0 ? 0 : v;
    return v >= n_nodes ? n_nodes - 1 : v;   // identity when data is sane
}

// ---------------------------------------------------------------------------
// T1 CSR build == two-level counting sort, bucket = dst>>9 (512 nodes/bucket).
// Pack: (d&511)<<17 | s  (requires n_nodes <= 131072; guarded at launch).
// ---------------------------------------------------------------------------

// bucket_count + cast_x fused. Blocks <512 do the LDS-hist count path
// (grid-stride fixed at 512*256); blocks >=512 cast x->bf16.
__global__ __launch_bounds__(256)
void bucket_count_castx_kernel(const void* __restrict__ ei, const int* __restrict__ flagp,
                               int* __restrict__ gcnt,
                               const float* __restrict__ x, __bf16* __restrict__ xb, int n4,
                               int n_edges, int n_nodes) {
    __shared__ int cnt[512];
    const int t = threadIdx.x;
    if (blockIdx.x < 512) {
        cnt[t] = 0; cnt[t + 256] = 0;
        __syncthreads();
        const int is64 = *flagp;
        for (int e = blockIdx.x * 256 + t; e < n_edges; e += 512 * 256) {
            int d = load_idx_clamped(ei, (long long)n_edges + e, is64, n_nodes);
            atomicAdd(&cnt[d >> 9], 1);
        }
        __syncthreads();
        if (cnt[t])       atomicAdd(&gcnt[t], cnt[t]);
        if (cnt[t + 256]) atomicAdd(&gcnt[t + 256], cnt[t + 256]);
    } else {
        const int nb = gridDim.x - 512;
        for (int i = (blockIdx.x - 512) * 256 + t; i < n4; i += nb * 256) {
            float4 v = ((const float4*)x)[i];
            bf16x4 o;
            o.x = (__bf16)v.x; o.y = (__bf16)v.y; o.z = (__bf16)v.z; o.w = (__bf16)v.w;
            ((bf16x4*)xb)[i] = o;
        }
    }
}

__global__ void bucket_scan_kernel(const int* __restrict__ gcnt, int* __restrict__ gbase,
                                   int* __restrict__ gcur, int n_edges) {
    __shared__ int sh[512];
    int t = threadIdx.x;
    int v = gcnt[t];
    sh[t] = v;
    __syncthreads();
    for (int off = 1; off < 512; off <<= 1) {
        int u = (t >= off) ? sh[t - off] : 0;
        __syncthreads();
        sh[t] += u;
        __syncthreads();
    }
    int excl = sh[t] - v;
    gbase[t] = excl;
    gcur[t]  = excl;
    if (t == 511) gbase[512] = n_edges;
}

__global__ __launch_bounds__(256)
void multisplit_kernel(const void* __restrict__ ei, const int* __restrict__ flagp,
                       int* __restrict__ gcur, unsigned* __restrict__ B,
                       int n_edges, int n_nodes) {
    __shared__ unsigned sv[4096];
    __shared__ unsigned dv[4096];
    __shared__ int cnt[512];
    __shared__ int cur[512];
    const int t = threadIdx.x;
    const int is64 = *flagp;
    const int ntiles = (n_edges + 4095) >> 12;
    for (int tile = blockIdx.x; tile < ntiles; tile += gridDim.x) {
        cnt[t] = 0; cnt[t + 256] = 0;
        __syncthreads();
        #pragma unroll
        for (int k = 0; k < 16; ++k) {
            int i = k * 256 + t;
            int e = (tile << 12) + i;
            unsigned dmark = 0xFFFFFFFFu, s = 0;
            if (e < n_edges) {
                s     = (unsigned)load_idx_clamped(ei, e, is64, n_nodes);
                int d = load_idx_clamped(ei, (long long)n_edges + e, is64, n_nodes);
                dmark = (unsigned)d;
                atomicAdd(&cnt[d >> 9], 1);
            }
            sv[i] = s; dv[i] = dmark;
        }
        __syncthreads();
        if (cnt[t])       cur[t]       = atomicAdd(&gcur[t], cnt[t]);
        if (cnt[t + 256]) cur[t + 256] = atomicAdd(&gcur[t + 256], cnt[t + 256]);
        __syncthreads();
        #pragma unroll
        for (int k = 0; k < 16; ++k) {
            int i = k * 256 + t;
            unsigned d = dv[i];
            if (d != 0xFFFFFFFFu) {
                int pos = atomicAdd(&cur[d >> 9], 1);
                pos = pos < 0 ? 0 : (pos >= n_edges ? n_edges - 1 : pos);
                B[pos] = ((d & 511u) << 17) | sv[i];
            }
        }
        __syncthreads();
    }
}

// R9: 512 threads/block, 1 node/thread (was 256 thr x 2 nodes). Halves the
// serial per-block hist/scan/place loop counts; 196 blocks < 256 CUs so
// block wall time IS kernel time. Single-variable chain probe.
__global__ __launch_bounds__(512)
void csr_build2_kernel(const unsigned* __restrict__ B, const int* __restrict__ gbase,
                       int* __restrict__ degc, int* __restrict__ offs,
                       float* __restrict__ dinv, int* __restrict__ csr,
                       int n_edges, int n_nodes) {
    __shared__ int cnt[512];
    __shared__ int scn[512];
    __shared__ int cur[512];
    const int b = blockIdx.x, t = threadIdx.x;
    cnt[t] = 0;
    __syncthreads();
    const int lo = gbase[b], hi = gbase[b + 1];
    for (int i = lo + t; i < hi; i += 512) {
        unsigned v = B[i];
        atomicAdd(&cnt[v >> 17], 1);
    }
    __syncthreads();
    int v = cnt[t];
    scn[t] = v;
    __syncthreads();
    for (int off = 1; off < 512; off <<= 1) {
        int u = (t >= off) ? scn[t - off] : 0;
        __syncthreads();
        scn[t] += u;
        __syncthreads();
    }
    int e0 = lo + scn[t] - v;
    cur[t] = e0;
    int n0 = b * 512 + t;
    if (n0 < n_nodes) {
        degc[n0] = v; offs[n0] = e0;
        dinv[n0] = 1.0f / fmaxf((float)v, 1.0f);
    }
    __syncthreads();
    for (int i = lo + t; i < hi; i += 512) {
        unsigned w = B[i];
        int pos = atomicAdd(&cur[w >> 17], 1);
        pos = pos < 0 ? 0 : (pos >= n_edges ? n_edges - 1 : pos);
        csr[pos] = (int)(w & 0x1FFFFu);
    }
}

// ---------------------------------------------------------------------------
// R4-proven FUSED gather+GEMM per layer (UNCHANGED). Per tile of 16 nodes:
// 16 lane-groups run the R3 gather loop (1 node/group, lane u owns feats
// 4u..4u+3), stage the 16x64 agg tile in LDS (rows padded to 72), sync, then
// the 4 waves each MFMA one 16-column tile (proven fragment mapping).
// ---------------------------------------------------------------------------
__global__ __launch_bounds__(256)
void fused_l1_kernel(const __bf16* __restrict__ xb,
                     const int* __restrict__ offs, const int* __restrict__ degc,
                     const float* __restrict__ dinv, const int* __restrict__ csr,
                     const __bf16* __restrict__ Bl, const __bf16* __restrict__ Br,
                     const float* __restrict__ bias,
                     __bf16* __restrict__ hout, int n_nodes) {
    const int t = threadIdx.x, lane = t & 63, wave = t >> 6;
    const int quad = lane >> 4, r16 = lane & 15;
    const int grp = t >> 4, u = t & 15;          // gather role: 16 groups/block
    bf16x8 bl[2], br[2];
    #pragma unroll
    for (int ks = 0; ks < 2; ++ks) {
        int f = wave * 16 + r16, k = ks * 32 + quad * 8;
        bl[ks] = *(const bf16x8*)(Bl + f * 64 + k);
        br[ks] = *(const bf16x8*)(Br + f * 64 + k);
    }
    const float bv = bias[wave * 16 + r16];
    __shared__ __bf16 sAgg[16][72];              // padded: 144B row stride
    const int ntiles = (n_nodes + 15) >> 4;
    for (int tile = blockIdx.x; tile < ntiles; tile += gridDim.x) {
        const int n = tile * 16 + grp;
        const bool act = n < n_nodes;
        float a0 = 0.f, a1 = 0.f, a2 = 0.f, a3 = 0.f, di = 1.f;
        if (act) {
            int rs = offs[n], cnt = degc[n];
            di = dinv[n];
            int idx = (u < cnt) ? (int)__builtin_nontemporal_load(&csr[rs + u]) : 0;
            int c = 0;
            while (true) {
                idx = idx < 0 ? 0 : (idx >= n_nodes ? n_nodes - 1 : idx);
                int sj[16];
                #pragma unroll
                for (int j = 0; j < 16; ++j) sj[j] = __shfl(idx, j, 16);
                bf16x4 v[16];
                #pragma unroll
                for (int j = 0; j < 16; ++j)
                    v[j] = ((const bf16x4*)xb)[(size_t)sj[j] * 16 + u];
                #pragma unroll
                for (int j = 0; j < 16; ++j) {
                    float m = (c + j < cnt) ? 1.f : 0.f;
                    a0 = fmaf(m, (float)v[j].x, a0);
                    a1 = fmaf(m, (float)v[j].y, a1);
                    a2 = fmaf(m, (float)v[j].z, a2);
                    a3 = fmaf(m, (float)v[j].w, a3);
                }
                c += 16;
                if (c >= cnt) break;
                idx = (u < cnt - c) ? (int)__builtin_nontemporal_load(&csr[rs + c + u]) : 0;
            }
        }
        bf16x4 o;
        o.x = (__bf16)(a0 * di); o.y = (__bf16)(a1 * di);
        o.z = (__bf16)(a2 * di); o.w = (__bf16)(a3 * di);
        *(bf16x4*)(&sAgg[grp][u * 4]) = o;       // same rounding as old agg path
        __syncthreads();
        // ---- MFMA phase (ct = wave) ----
        const int m0 = tile * 16;
        int mrow = m0 + r16; if (mrow >= n_nodes) mrow = n_nodes - 1;
        bf16x8 ag[2], ax[2];
        #pragma unroll
        for (int ks = 0; ks < 2; ++ks) {
            ag[ks] = *(const bf16x8*)(&sAgg[r16][ks * 32 + quad * 8]);
            ax[ks] = *(const bf16x8*)(xb + (size_t)mrow * 64 + ks * 32 + quad * 8);
        }
        f32x4 acc = {0.f, 0.f, 0.f, 0.f};
        acc = __builtin_amdgcn_mfma_f32_16x16x32_bf16(ag[0], bl[0], acc, 0, 0, 0);
        acc = __builtin_amdgcn_mfma_f32_16x16x32_bf16(ag[1], bl[1], acc, 0, 0, 0);
        acc = __builtin_amdgcn_mfma_f32_16x16x32_bf16(ax[0], br[0], acc, 0, 0, 0);
        acc = __builtin_amdgcn_mfma_f32_16x16x32_bf16(ax[1], br[1], acc, 0, 0, 0);
        const int col = wave * 16 + r16;
        #pragma unroll
        for (int rg = 0; rg < 4; ++rg) {
            int row = m0 + quad * 4 + rg;
            if (row < n_nodes) {
                float ov = acc[rg] + bv;
                hout[(size_t)row * 64 + col] = (__bf16)fmaxf(ov, 0.f);
            }
        }
        __syncthreads();                          // protect sAgg before next tile
    }
}

__global__ __launch_bounds__(256)
void fused_l2_kernel(const __bf16* __restrict__ hb,
                     const int* __restrict__ offs, const int* __restrict__ degc,
                     const float* __restrict__ dinv, const int* __restrict__ csr,
                     const __bf16* __restrict__ Bl, const __bf16* __restrict__ Br,
                     const float* __restrict__ bias,
                     float* __restrict__ out, int n_nodes) {
    const int t = threadIdx.x, lane = t & 63, wave = t >> 6;
    const int quad = lane >> 4, r16 = lane & 15;
    const int grp = t >> 4, u = t & 15;
    bf16x8 bl[2], br[2];
    #pragma unroll
    for (int ks = 0; ks < 2; ++ks) {
        int f = wave * 16 + r16, k = ks * 32 + quad * 8;
        bl[ks] = *(const bf16x8*)(Bl + f * 64 + k);
        br[ks] = *(const bf16x8*)(Br + f * 64 + k);
    }
    const float bv = bias[wave * 16 + r16];
    __shared__ __bf16 sAgg[16][72];
    const int ntiles = (n_nodes + 15) >> 4;
    for (int tile = blockIdx.x; tile < ntiles; tile += gridDim.x) {
        const int n = tile * 16 + grp;
        const bool act = n < n_nodes;
        float a0 = 0.f, a1 = 0.f, a2 = 0.f, a3 = 0.f, di = 1.f;
        if (act) {
            int rs = offs[n], cnt = degc[n];
            di = dinv[n];
            int idx = (u < cnt) ? (int)__builtin_nontemporal_load(&csr[rs + u]) : 0;
            int c = 0;
            while (true) {
                idx = idx < 0 ? 0 : (idx >= n_nodes ? n_nodes - 1 : idx);
                int sj[16];
                #pragma unroll
                for (int j = 0; j < 16; ++j) sj[j] = __shfl(idx, j, 16);
                bf16x4 v[16];
                #pragma unroll
                for (int j = 0; j < 16; ++j)
                    v[j] = ((const bf16x4*)hb)[(size_t)sj[j] * 16 + u];
                #pragma unroll
                for (int j = 0; j < 16; ++j) {
                    float m = (c + j < cnt) ? 1.f : 0.f;
                    a0 = fmaf(m, (float)v[j].x, a0);
                    a1 = fmaf(m, (float)v[j].y, a1);
                    a2 = fmaf(m, (float)v[j].z, a2);
                    a3 = fmaf(m, (float)v[j].w, a3);
                }
                c += 16;
                if (c >= cnt) break;
                idx = (u < cnt - c) ? (int)__builtin_nontemporal_load(&csr[rs + c + u]) : 0;
            }
        }
        bf16x4 o;
        o.x = (__bf16)(a0 * di); o.y = (__bf16)(a1 * di);
        o.z = (__bf16)(a2 * di); o.w = (__bf16)(a3 * di);
        *(bf16x4*)(&sAgg[grp][u * 4]) = o;
        __syncthreads();
        const int m0 = tile * 16;
        int mrow = m0 + r16; if (mrow >= n_nodes) mrow = n_nodes - 1;
        bf16x8 ag[2], ah[2];
        #pragma unroll
        for (int ks = 0; ks < 2; ++ks) {
            ag[ks] = *(const bf16x8*)(&sAgg[r16][ks * 32 + quad * 8]);
            ah[ks] = *(const bf16x8*)(hb + (size_t)mrow * 64 + ks * 32 + quad * 8);
        }
        f32x4 acc = {0.f, 0.f, 0.f, 0.f};
        acc = __builtin_amdgcn_mfma_f32_16x16x32_bf16(ag[0], bl[0], acc, 0, 0, 0);
        acc = __builtin_amdgcn_mfma_f32_16x16x32_bf16(ag[1], bl[1], acc, 0, 0, 0);
        acc = __builtin_amdgcn_mfma_f32_16x16x32_bf16(ah[0], br[0], acc, 0, 0, 0);
        acc = __builtin_amdgcn_mfma_f32_16x16x32_bf16(ah[1], br[1], acc, 0, 0, 0);
        const int col = wave * 16 + r16;
        #pragma unroll
        for (int rg = 0; rg < 4; ++rg) {
            int row = m0 + quad * 4 + rg;
            if (row < n_nodes) out[(size_t)row * 64 + col] = acc[rg] + bv;
        }
        __syncthreads();
    }
}

// ---------------------------------------------------------------------------
// Scans (T3/T4 paths)
// ---------------------------------------------------------------------------
__global__ __launch_bounds__(256)
void scan_partial_kernel(const int* __restrict__ degc, int* __restrict__ part, int n_nodes) {
    __shared__ int sh[256];
    int i = blockIdx.x * 256 + threadIdx.x;
    sh[threadIdx.x] = (i < n_nodes) ? degc[i] : 0;
    __syncthreads();
    for (int off = 128; off > 0; off >>= 1) {
        if (threadIdx.x < off) sh[threadIdx.x] += sh[threadIdx.x + off];
        __syncthreads();
    }
    if (threadIdx.x == 0) part[blockIdx.x] = sh[0];
}

__global__ void scan_top_kernel(int* __restrict__ part, int nparts) {
    __shared__ int sh[512];
    int t = threadIdx.x;
    int v = (t < nparts) ? part[t] : 0;
    sh[t] = v;
    __syncthreads();
    for (int off = 1; off < 512; off <<= 1) {
        int u = (t >= off) ? sh[t - off] : 0;
        __syncthreads();
        sh[t] += u;
        __syncthreads();
    }
    if (t < nparts) part[t] = sh[t] - v;   // exclusive
}

__global__ __launch_bounds__(256)
void scan_final_kernel(const int* __restrict__ degc, const int* __restrict__ part,
                       int* __restrict__ offs, float* __restrict__ deg_inv, int n_nodes) {
    __shared__ int sh[256];
    int t = threadIdx.x;
    int i = blockIdx.x * 256 + t;
    int v = (i < n_nodes) ? degc[i] : 0;
    sh[t] = v;
    __syncthreads();
    for (int off = 1; off < 256; off <<= 1) {
        int u = (t >= off) ? sh[t - off] : 0;
        __syncthreads();
        sh[t] += u;
        __syncthreads();
    }
    if (i < n_nodes) {
        offs[i]    = sh[t] - v + part[blockIdx.x];
        deg_inv[i] = 1.0f / fmaxf((float)v, 1.0f);
    }
}

// ---------------------------------------------------------------------------
// T3 path: global-atomic hist + cursor scatter.
// ---------------------------------------------------------------------------
__global__ __launch_bounds__(256)
void hist_kernel(const void* __restrict__ ei, const int* __restrict__ flagp,
                 int* __restrict__ degc, int n_edges, int n_nodes) {
    int e = blockIdx.x * 256 + threadIdx.x;
    if (e >= n_edges) return;
    int d = load_idx_clamped(ei, (long long)n_edges + e, *flagp, n_nodes);
    atomicAdd(&degc[d], 1);
}

__global__ __launch_bounds__(256)
void csr_scatter_kernel(const void* __restrict__ ei, const int* __restrict__ flagp,
                        const int* __restrict__ offs, int* __restrict__ cursor,
                        int* __restrict__ csr, int n_edges, int n_nodes) {
    int e = blockIdx.x * 256 + threadIdx.x;
    if (e >= n_edges) return;
    int is64 = *flagp;
    int s = load_idx_clamped(ei, e, is64, n_nodes);
    int d = load_idx_clamped(ei, (long long)n_edges + e, is64, n_nodes);
    int pos = offs[d] + atomicAdd(&cursor[d], 1);
    pos = pos < 0 ? 0 : (pos >= n_edges ? n_edges - 1 : pos);
    csr[pos] = s;
}

// ---------------------------------------------------------------------------
// Casts (T3 fallback path)
// ---------------------------------------------------------------------------
__global__ __launch_bounds__(256)
void cast_w_kernel(const float* __restrict__ a, const float* __restrict__ b,
                   const float* __restrict__ c, const float* __restrict__ d,
                   __bf16* __restrict__ o) {
    int i = blockIdx.x * 256 + threadIdx.x;
    if (i < FEAT * FEAT) {
        o[i]         = (__bf16)a[i];
        o[4096 + i]  = (__bf16)b[i];
        o[8192 + i]  = (__bf16)c[i];
        o[12288 + i] = (__bf16)d[i];
    }
}

// ---------------------------------------------------------------------------
// Standalone gather kernels (T3 fallback path; unchanged, proven).
// ---------------------------------------------------------------------------
__global__ __launch_bounds__(256)
void gather_bf16_kernel(const __bf16* __restrict__ hin, const int* __restrict__ offs,
                        const int* __restrict__ degc, const float* __restrict__ dinv,
                        const int* __restrict__ csr, __bf16* __restrict__ agg,
                        int n_nodes) {
    const int t = threadIdx.x, u = t & 15;
    const int g0 = blockIdx.x * 16 + (t >> 4);
    const int ng = gridDim.x * 16;
    if (g0 >= n_nodes) return;
    int rs = offs[g0], cnt = degc[g0];
    float di = dinv[g0];
    int idx = (u < cnt) ? (int)__builtin_nontemporal_load(&csr[rs + u]) : 0;
    for (int n = g0; n < n_nodes; n += ng) {
        const int nn = n + ng;
        int rs2 = 0, cnt2 = 0;
        float di2 = 1.0f;
        if (nn < n_nodes) { rs2 = offs[nn]; cnt2 = degc[nn]; di2 = dinv[nn]; }
        float a0 = 0.f, a1 = 0.f, a2 = 0.f, a3 = 0.f;
        int c = 0;
        while (true) {
            idx = idx < 0 ? 0 : (idx >= n_nodes ? n_nodes - 1 : idx);
            int sj[16];
            #pragma unroll
            for (int j = 0; j < 16; ++j) sj[j] = __shfl(idx, j, 16);
            bf16x4 v[16];
            #pragma unroll
            for (int j = 0; j < 16; ++j)
                v[j] = ((const bf16x4*)hin)[(size_t)sj[j] * 16 + u];
            #pragma unroll
            for (int j = 0; j < 16; ++j) {
                float m = (c + j < cnt) ? 1.f : 0.f;
                a0 = fmaf(m, (float)v[j].x, a0);
                a1 = fmaf(m, (float)v[j].y, a1);
                a2 = fmaf(m, (float)v[j].z, a2);
                a3 = fmaf(m, (float)v[j].w, a3);
            }
            c += 16;
            if (c >= cnt) break;
            idx = (u < cnt - c) ? (int)__builtin_nontemporal_load(&csr[rs + c + u]) : 0;
        }
        idx = (nn < n_nodes && u < cnt2)
                  ? (int)__builtin_nontemporal_load(&csr[rs2 + u]) : 0;
        bf16x4 o;
        o.x = (__bf16)(a0 * di); o.y = (__bf16)(a1 * di);
        o.z = (__bf16)(a2 * di); o.w = (__bf16)(a3 * di);
        ((bf16x4*)agg)[(size_t)n * 16 + u] = o;
        rs = rs2; cnt = cnt2; di = di2;
    }
}

__global__ __launch_bounds__(256)
void gather_f32_kernel(const float* __restrict__ xin, const int* __restrict__ offs,
                       const int* __restrict__ degc, const float* __restrict__ dinv,
                       const int* __restrict__ csr, __bf16* __restrict__ agg,
                       int n_nodes) {
    const int t = threadIdx.x, lane = t & 63, g = lane >> 4, u = lane & 15;
    const int gw = blockIdx.x * 4 + (t >> 6), nw = gridDim.x * 4;
    for (int n = gw; n < n_nodes; n += nw) {
        int rs = offs[n], cnt = degc[n];
        float a0 = 0.f, a1 = 0.f, a2 = 0.f, a3 = 0.f;
        for (int c = 0; c < cnt; c += 64) {
            int chunk = min(64, cnt - c);
            int myid = (lane < chunk) ? (int)__builtin_nontemporal_load(&csr[rs + c + lane]) : 0;
            myid = myid < 0 ? 0 : (myid >= n_nodes ? n_nodes - 1 : myid);
            for (int q = 0; q < chunk; q += 16) {
                int q0 = q + g, q1 = q + g + 4, q2 = q + g + 8, q3 = q + g + 12;
                int s0 = __shfl(myid, q0), s1 = __shfl(myid, q1);
                int s2 = __shfl(myid, q2), s3 = __shfl(myid, q3);
                float m0 = (q0 < chunk) ? 1.f : 0.f;
                float m1 = (q1 < chunk) ? 1.f : 0.f;
                float m2 = (q2 < chunk) ? 1.f : 0.f;
                float m3 = (q3 < chunk) ? 1.f : 0.f;
                float4 v0 = ((const float4*)xin)[(size_t)s0 * 16 + u];
                float4 v1 = ((const float4*)xin)[(size_t)s1 * 16 + u];
                float4 v2 = ((const float4*)xin)[(size_t)s2 * 16 + u];
                float4 v3 = ((const float4*)xin)[(size_t)s3 * 16 + u];
                a0 = fmaf(m0, v0.x, a0); a1 = fmaf(m0, v0.y, a1);
                a2 = fmaf(m0, v0.z, a2); a3 = fmaf(m0, v0.w, a3);
                a0 = fmaf(m1, v1.x, a0); a1 = fmaf(m1, v1.y, a1);
                a2 = fmaf(m1, v1.z, a2); a3 = fmaf(m1, v1.w, a3);
                a0 = fmaf(m2, v2.x, a0); a1 = fmaf(m2, v2.y, a1);
                a2 = fmaf(m2, v2.z, a2); a3 = fmaf(m2, v2.w, a3);
                a0 = fmaf(m3, v3.x, a0); a1 = fmaf(m3, v3.y, a1);
                a2 = fmaf(m3, v3.z, a2); a3 = fmaf(m3, v3.w, a3);
            }
        }
        a0 += __shfl_xor(a0, 16); a1 += __shfl_xor(a1, 16);
        a2 += __shfl_xor(a2, 16); a3 += __shfl_xor(a3, 16);
        a0 += __shfl_xor(a0, 32); a1 += __shfl_xor(a1, 32);
        a2 += __shfl_xor(a2, 32); a3 += __shfl_xor(a3, 32);
        if (g == 0) {
            float di = dinv[n];
            bf16x4 o;
            o.x = (__bf16)(a0 * di); o.y = (__bf16)(a1 * di);
            o.z = (__bf16)(a2 * di); o.w = (__bf16)(a3 * di);
            ((bf16x4*)agg)[(size_t)n * 16 + u] = o;
        }
    }
}

// ---------------------------------------------------------------------------
// Standalone MFMA GEMMs (T3 fallback path; unchanged, proven).
// ---------------------------------------------------------------------------
__global__ __launch_bounds__(256)
void gemm_l1_kernel(const __bf16* __restrict__ Ag, const float* __restrict__ xin,
                    const __bf16* __restrict__ Bl, const __bf16* __restrict__ Br,
                    const float* __restrict__ bias,
                    __bf16* __restrict__ hout, int n_nodes) {
    const int t = threadIdx.x, lane = t & 63;
    const int quad = lane >> 4, r16 = lane & 15;
    bf16x8 bl[2][4], br[2][4];
    #pragma unroll
    for (int ks = 0; ks < 2; ++ks)
        #pragma unroll
        for (int ct = 0; ct < 4; ++ct) {
            int f = ct * 16 + r16, k = ks * 32 + quad * 8;
            bl[ks][ct] = *(const bf16x8*)(Bl + f * 64 + k);
            br[ks][ct] = *(const bf16x8*)(Br + f * 64 + k);
        }
    const int m0 = (blockIdx.x * 4 + (t >> 6)) * 16;
    if (m0 >= n_nodes) return;
    int mrow = m0 + r16; if (mrow >= n_nodes) mrow = n_nodes - 1;
    bf16x8 ag[2], ax[2];
    #pragma unroll
    for (int ks = 0; ks < 2; ++ks) {
        ag[ks] = *(const bf16x8*)(Ag + (size_t)mrow * 64 + ks * 32 + quad * 8);
        const float* xr = xin + (size_t)mrow * 64 + ks * 32 + quad * 8;
        float4 p = *(const float4*)xr;
        float4 q = *(const float4*)(xr + 4);
        union { bf16x8 v; __bf16 e[8]; } U;
        U.e[0] = (__bf16)p.x; U.e[1] = (__bf16)p.y; U.e[2] = (__bf16)p.z; U.e[3] = (__bf16)p.w;
        U.e[4] = (__bf16)q.x; U.e[5] = (__bf16)q.y; U.e[6] = (__bf16)q.z; U.e[7] = (__bf16)q.w;
        ax[ks] = U.v;
    }
    #pragma unroll
    for (int ct = 0; ct < 4; ++ct) {
        f32x4 acc = {0.f, 0.f, 0.f, 0.f};
        acc = __builtin_amdgcn_mfma_f32_16x16x32_bf16(ag[0], bl[0][ct], acc, 0, 0, 0);
        acc = __builtin_amdgcn_mfma_f32_16x16x32_bf16(ag[1], bl[1][ct], acc, 0, 0, 0);
        acc = __builtin_amdgcn_mfma_f32_16x16x32_bf16(ax[0], br[0][ct], acc, 0, 0, 0);
        acc = __builtin_amdgcn_mfma_f32_16x16x32_bf16(ax[1], br[1][ct], acc, 0, 0, 0);
        int col = ct * 16 + r16;
        float bv = bias[col];
        #pragma unroll
        for (int rg = 0; rg < 4; ++rg) {
            int n = m0 + quad * 4 + rg;
            if (n < n_nodes) {
                float o = acc[rg] + bv;
                hout[(size_t)n * 64 + col] = (__bf16)fmaxf(o, 0.f);
            }
        }
    }
}

__global__ __launch_bounds__(256)
void gemm_l2_kernel(const __bf16* __restrict__ Ag, const __bf16* __restrict__ Ah,
                    const __bf16* __restrict__ Bl, const __bf16* __restrict__ Br,
                    const float* __restrict__ bias,
                    float* __restrict__ out, int n_nodes) {
    const int t = threadIdx.x, lane = t & 63;
    const int quad = lane >> 4, r16 = lane & 15;
    bf16x8 bl[2][4], br[2][4];
    #pragma unroll
    for (int ks = 0; ks < 2; ++ks)
        #pragma unroll
        for (int ct = 0; ct < 4; ++ct) {
            int f = ct * 16 + r16, k = ks * 32 + quad * 8;
            bl[ks][ct] = *(const bf16x8*)(Bl + f * 64 + k);
            br[ks][ct] = *(const bf16x8*)(Br + f * 64 + k);
        }
    const int m0 = (blockIdx.x * 4 + (t >> 6)) * 16;
    if (m0 >= n_nodes) return;
    int mrow = m0 + r16; if (mrow >= n_nodes) mrow = n_nodes - 1;
    bf16x8 ag[2], ah[2];
    #pragma unroll
    for (int ks = 0; ks < 2; ++ks) {
        ag[ks] = *(const bf16x8*)(Ag + (size_t)mrow * 64 + ks * 32 + quad * 8);
        ah[ks] = *(const bf16x8*)(Ah + (size_t)mrow * 64 + ks * 32 + quad * 8);
    }
    #pragma unroll
    for (int ct = 0; ct < 4; ++ct) {
        f32x4 acc = {0.f, 0.f, 0.f, 0.f};
        acc = __builtin_amdgcn_mfma_f32_16x16x32_bf16(ag[0], bl[0][ct], acc, 0, 0, 0);
        acc = __builtin_amdgcn_mfma_f32_16x16x32_bf16(ag[1], bl[1][ct], acc, 0, 0, 0);
        acc = __builtin_amdgcn_mfma_f32_16x16x32_bf16(ah[0], br[0][ct], acc, 0, 0, 0);
        acc = __builtin_amdgcn_mfma_f32_16x16x32_bf16(ah[1], br[1][ct], acc, 0, 0, 0);
        int col = ct * 16 + r16;
        float bv = bias[col];
        #pragma unroll
        for (int rg = 0; rg < 4; ++rg) {
            int n = m0 + quad * 4 + rg;
            if (n < n_nodes) out[(size_t)n * 64 + col] = acc[rg] + bv;
        }
    }
}

// ---------------------------------------------------------------------------
// T4 fallback: fused LDS kernels (unchanged).
// ---------------------------------------------------------------------------
__global__ __launch_bounds__(256)
void sage_fused_l1_kernel(const float* __restrict__ xin,
                          const int* __restrict__ offs, const int* __restrict__ degc,
                          const float* __restrict__ deg_inv, const int* __restrict__ csr,
                          const float* __restrict__ Wl, const float* __restrict__ bias,
                          const float* __restrict__ Wr,
                          __bf16* __restrict__ hout, int n_nodes) {
    __shared__ float WlT[FEAT * 65], WrT[FEAT * 65], bsh[FEAT];
    __shared__ float aggS[4][FEAT], selfS[4][FEAT];
    const int t = threadIdx.x;
    #pragma unroll
    for (int p = 0; p < 16; ++p) {
        int i = t + p * 256, j = i >> 6, k = i & 63;
        WlT[k * 65 + j] = Wl[i];
        WrT[k * 65 + j] = Wr[i];
    }
    if (t < FEAT) bsh[t] = bias[t];
    __syncthreads();
    const int w = t >> 6, f = t & 63;
    const int n_groups = (n_nodes + 3) >> 2;
    for (int g = blockIdx.x; g < n_groups; g += gridDim.x) {
        int n = g * 4 + w;
        bool act = (n < n_nodes);
        if (act) {
            int rs = offs[n], cnt = degc[n];
            float acc = 0.f;
            for (int c = 0; c < cnt; c += 64) {
                int chunk = min(64, cnt - c);
                int myid = (f < chunk) ? csr[rs + c + f] : 0;
                #pragma unroll 4
                for (int q = 0; q < chunk; ++q) {
                    int s = __shfl(myid, q);
                    acc += xin[(long long)s * FEAT + f];
                }
            }
            aggS[w][f]  = acc * deg_inv[n];
            selfS[w][f] = xin[(long long)n * FEAT + f];
        }
        __syncthreads();
        if (act) {
            float o = bsh[f];
            #pragma unroll
            for (int k = 0; k < FEAT; ++k) {
                o = fmaf(aggS[w][k],  WlT[k * 65 + f], o);
                o = fmaf(selfS[w][k], WrT[k * 65 + f], o);
            }
            o = fmaxf(o, 0.f);
            hout[(long long)n * FEAT + f] = (__bf16)o;
        }
        __syncthreads();
    }
}

__global__ __launch_bounds__(256)
void sage_fused_l2_kernel(const __bf16* __restrict__ hin,
                          const int* __restrict__ offs, const int* __restrict__ degc,
                          const float* __restrict__ deg_inv, const int* __restrict__ csr,
                          const float* __restrict__ Wl, const float* __restrict__ bias,
                          const float* __restrict__ Wr,
                          float* __restrict__ out, int n_nodes) {
    __shared__ float WlT[FEAT * 65], WrT[FEAT * 65], bsh[FEAT];
    __shared__ float aggS[4][FEAT], selfS[4][FEAT];
    const int t = threadIdx.x;
    #pragma unroll
    for (int p = 0; p < 16; ++p) {
        int i = t + p * 256, j = i >> 6, k = i & 63;
        WlT[k * 65 + j] = Wl[i];
        WrT[k * 65 + j] = Wr[i];
    }
    if (t < FEAT) bsh[t] = bias[t];
    __syncthreads();
    const int w = t >> 6, f = t & 63;
    const int n_groups = (n_nodes + 3) >> 2;
    for (int g = blockIdx.x; g < n_groups; g += gridDim.x) {
        int n = g * 4 + w;
        bool act = (n < n_nodes);
        if (act) {
            int rs = offs[n], cnt = degc[n];
            float acc = 0.f;
            for (int c = 0; c < cnt; c += 64) {
                int chunk = min(64, cnt - c);
                int myid = (f < chunk) ? csr[rs + c + f] : 0;
                #pragma unroll 4
                for (int q = 0; q < chunk; ++q) {
                    int s = __shfl(myid, q);
                    acc += (float)hin[(long long)s * FEAT + f];
                }
            }
            aggS[w][f]  = acc * deg_inv[n];
            selfS[w][f] = (float)hin[(long long)n * FEAT + f];
        }
        __syncthreads();
        if (act) {
            float o = bsh[f];
            #pragma unroll
            for (int k = 0; k < FEAT; ++k) {
                o = fmaf(aggS[w][k],  WlT[k * 65 + f], o);
                o = fmaf(selfS[w][k], WrT[k * 65 + f], o);
            }
            out[(long long)n * FEAT + f] = o;
        }
        __syncthreads();
    }
}

// ---------------------------------------------------------------------------
// Launch
// ---------------------------------------------------------------------------
extern "C" void kernel_launch(void* const* d_in, const int* in_sizes, int n_in,
                              void* d_out, int out_size, void* d_ws, size_t ws_size,
                              hipStream_t stream) {
    const float* x   = (const float*)d_in[0];
    const void*  ei  = d_in[1];
    const float* W1l = (const float*)d_in[2];
    const float* b1  = (const float*)d_in[3];
    const float* W1r = (const float*)d_in[4];
    const float* W2l = (const float*)d_in[5];
    const float* b2  = (const float*)d_in[6];
    const float* W2r = (const float*)d_in[7];
    float* out = (float*)d_out;

    const int n_nodes = in_sizes[0] / FEAT;
    const int n_edges = in_sizes[1] / 2;
    const int nparts  = (n_nodes + 255) / 256;     // <= 512
    const int egrid   = (n_edges + 255) / 256;
    const int NB      = (n_nodes + 511) >> 9;      // buckets of 512 nodes

    char* ws = (char*)d_ws;
    auto al = [](size_t v) { return (v + 255) & ~(size_t)255; };

    // ---- T1 layout (two-level counting sort) ----
    size_t o = 0;
    int*      flag  = (int*)(ws + o);      o += 256;
    int*      degc  = (int*)(ws + o);      o += al((size_t)n_nodes * 4);
    float*    dinv  = (float*)(ws + o);    o += al((size_t)n_nodes * 4);
    int*      offs  = (int*)(ws + o);      o += al((size_t)n_nodes * 4);
    int*      gcnt  = (int*)(ws + o);      o += al(512 * 4);
    int*      gbase = (int*)(ws + o);      o += al(513 * 4);
    int*      gcur  = (int*)(ws + o);      o += al(512 * 4);
    unsigned* B     = (unsigned*)(ws + o); o += al((size_t)n_edges * 4);
    int*      csr   = (int*)(ws + o);      o += al((size_t)n_edges * 4);
    __bf16*   xb    = (__bf16*)(ws + o);   o += al((size_t)n_nodes * FEAT * 2);
    __bf16*   wb    = (__bf16*)(ws + o);   o += al((size_t)4 * FEAT * FEAT * 2);
    __bf16*   h     = (__bf16*)(ws + o);   o += al((size_t)n_nodes * FEAT * 2);
    const size_t needT1 = o;

    // ---- T3 layout (proven fallback) ----
    size_t o3 = 0;
    int*    flag3   = (int*)(ws + o3);    o3 += 256;
    int*    degc3   = (int*)(ws + o3);    o3 += al((size_t)n_nodes * 4);
    float*  dinv3   = (float*)(ws + o3);  o3 += al((size_t)n_nodes * 4);
    int*    offs3   = (int*)(ws + o3);    o3 += al((size_t)n_nodes * 4);
    int*    cursor3 = (int*)(ws + o3);    o3 += al((size_t)n_nodes * 4);
    int*    part3   = (int*)(ws + o3);    o3 += al(2048);
    int*    csr3    = (int*)(ws + o3);    o3 += al((size_t)n_edges * 4);
    const size_t commonEnd3 = o3;
    __bf16* wb3  = (__bf16*)(ws + o3);    o3 += al((size_t)4 * FEAT * FEAT * 2);
    __bf16* agg3 = (__bf16*)(ws + o3);    o3 += al((size_t)n_nodes * FEAT * 2);
    __bf16* h3   = (__bf16*)(ws + o3);    o3 += al((size_t)n_nodes * FEAT * 2);
    const size_t needT3 = o3;

    const int n4 = n_nodes * FEAT / 4;
    const int mgrid = (n_nodes + 63) / 64;
    const int ggrid = 2048;
    const int ntiles = (n_edges + 4095) >> 12;
    const int ftiles = (n_nodes + 15) >> 4;
    const int fgrid2 = ftiles < 2048 ? ftiles : 2048;

    if (ws_size >= needT1 && n_nodes <= 131072) {
        detect_castw_kernel<<<17, 256, 0, stream>>>((const unsigned*)ei, flag, gcnt,
                                                    W1l, W1r, W2l, W2r, wb);
        bucket_count_castx_kernel<<<1536, 256, 0, stream>>>(ei, flag, gcnt,
                                                            x, xb, n4, n_edges, n_nodes);
        bucket_scan_kernel<<<1, 512, 0, stream>>>(gcnt, gbase, gcur, n_edges);
        multisplit_kernel<<<ntiles, 256, 0, stream>>>(ei, flag, gcur, B, n_edges, n_nodes);
        csr_build2_kernel<<<NB, 512, 0, stream>>>(B, gbase, degc, offs, dinv, csr, n_edges, n_nodes);
        fused_l1_kernel<<<fgrid2, 256, 0, stream>>>(xb, offs, degc, dinv, csr,
                                                    wb, wb + 4096, b1, h, n_nodes);
        fused_l2_kernel<<<fgrid2, 256, 0, stream>>>(h, offs, degc, dinv, csr,
                                                    wb + 8192, wb + 12288, b2, out, n_nodes);
    } else if (ws_size >= needT3) {
        zero2_kernel<<<nparts, 256, 0, stream>>>(degc3, cursor3, n_nodes);
        detect_idx_kernel<<<1, 256, 0, stream>>>((const unsigned*)ei, flag3, part3);
        hist_kernel<<<egrid, 256, 0, stream>>>(ei, flag3, degc3, n_edges, n_nodes);
        scan_partial_kernel<<<nparts, 256, 0, stream>>>(degc3, part3, n_nodes);
        scan_top_kernel<<<1, 512, 0, stream>>>(part3, nparts);
        scan_final_kernel<<<nparts, 256, 0, stream>>>(degc3, part3, offs3, dinv3, n_nodes);
        csr_scatter_kernel<<<egrid, 256, 0, stream>>>(ei, flag3, offs3, cursor3, csr3, n_edges, n_nodes);
        cast_w_kernel<<<16, 256, 0, stream>>>(W1l, W1r, W2l, W2r, wb3);
        gather_f32_kernel<<<ggrid, 256, 0, stream>>>(x, offs3, degc3, dinv3, csr3, agg3, n_nodes);
        gemm_l1_kernel<<<mgrid, 256, 0, stream>>>(agg3, x, wb3, wb3 + 4096, b1, h3, n_nodes);
        gather_bf16_kernel<<<ggrid, 256, 0, stream>>>(h3, offs3, degc3, dinv3, csr3, agg3, n_nodes);
        gemm_l2_kernel<<<mgrid, 256, 0, stream>>>(agg3, h3, wb3 + 8192, wb3 + 12288, b2, out, n_nodes);
    } else {
        __bf16* hf = (__bf16*)(ws + commonEnd3);
        zero2_kernel<<<nparts, 256, 0, stream>>>(degc3, cursor3, n_nodes);
        detect_idx_kernel<<<1, 256, 0, stream>>>((const unsigned*)ei, flag3, part3);
        hist_kernel<<<egrid, 256, 0, stream>>>(ei, flag3, degc3, n_edges, n_nodes);
        scan_partial_kernel<<<nparts, 256, 0, stream>>>(degc3, part3, n_nodes);
        scan_top_kernel<<<1, 512, 0, stream>>>(part3, nparts);
        scan_final_kernel<<<nparts, 256, 0, stream>>>(degc3, part3, offs3, dinv3, n_nodes);
        csr_scatter_kernel<<<egrid, 256, 0, stream>>>(ei, flag3, offs3, cursor3, csr3, n_edges, n_nodes);
        const int n_groups = (n_nodes + 3) / 4;
        const int fgrid = n_groups < 4096 ? n_groups : 4096;
        sage_fused_l1_kernel<<<fgrid, 256, 0, stream>>>(x, offs3, degc3, dinv3, csr3,
                                                        W1l, b1, W1r, hf, n_nodes);
        sage_fused_l2_kernel<<<fgrid, 256, 0, stream>>>(hf, offs3, degc3, dinv3, csr3,
                                                        W2l, b2, W2r, out, n_nodes);
    }
}